// Round 6
// baseline (461.732 us; speedup 1.0000x reference)
//
#include <hip/hip_runtime.h>
#include <hip/hip_bf16.h>

#define N_NODES 50000
#define N_EDGES 800000
#define C_IN 128
#define C_OUT 256
#define BN_EPS 1e-5f
#define NBLK ((N_NODES + 255) / 256)   // 196 scan blocks
#define SL 8                           // channel slices (== XCD count)
#define SLC 32                         // channels per slice
#define NPB 128                        // nodes per gather block (32/wave)
#define PAD 8                          // LDS row pad (bf16 elems, keeps 16B align)

using short8  = __attribute__((ext_vector_type(8))) short;
using floatx4 = __attribute__((ext_vector_type(4))) float;

union UB2 { unsigned int u; __hip_bfloat162 b; };

// fp32 -> bf16 round-to-nearest-even
__device__ __forceinline__ unsigned short f2bf(float f) {
    unsigned int u = __float_as_uint(f);
    u = (u + 0x7fffu + ((u >> 16) & 1u)) >> 16;
    return (unsigned short)u;
}
__device__ __forceinline__ float bflo(unsigned int w) {
    return __uint_as_float(w << 16);
}
__device__ __forceinline__ float bfhi(unsigned int w) {
    return __uint_as_float(w & 0xFFFF0000u);
}

// ---------------------------------------------------------------------------
// Converts: x -> bf16 [N,128]; W' = [theta ; phi-theta] -> bf16 [512,128].
// Identity: theta@(xj-xi) + phi@xi = u[dst] + v[src]; relu/max commute so the
// edge pass only needs max over u rows.
// ---------------------------------------------------------------------------
__global__ __launch_bounds__(256) void convert_x(
    const float* __restrict__ x, unsigned short* __restrict__ xb)
{
    int i = blockIdx.x * 256 + threadIdx.x;
    if (i < N_NODES * C_IN / 4) {
        float4 vv = ((const float4*)x)[i];
        ((ushort4*)xb)[i] = make_ushort4(f2bf(vv.x), f2bf(vv.y),
                                         f2bf(vv.z), f2bf(vv.w));
    }
}

__global__ __launch_bounds__(256) void convert_w(
    const float* __restrict__ theta, const float* __restrict__ phi,
    unsigned short* __restrict__ wb)
{
    int i = blockIdx.x * 256 + threadIdx.x;       // float4 index over [512][128]
    if (i >= 512 * C_IN / 4) return;
    float4 t;
    if (i < 256 * C_IN / 4) {
        t = ((const float4*)theta)[i];
    } else {
        int j = i - 256 * C_IN / 4;
        float4 th = ((const float4*)theta)[j];
        float4 ph = ((const float4*)phi)[j];
        t = make_float4(ph.x - th.x, ph.y - th.y, ph.z - th.z, ph.w - th.w);
    }
    ((ushort4*)wb)[i] = make_ushort4(f2bf(t.x), f2bf(t.y), f2bf(t.z), f2bf(t.w));
}

// ---------------------------------------------------------------------------
// MFMA GEMM: M=50000, N=512, K=128. Block tile 128x64, K fully staged.
// Outputs slice-major u (bf16) / v (bf16) for the XCD-local gather.
// Verified layouts: A-frag A[m=lane&15][k=quad*8+j]; B-frag B[k][n=lane&15];
// C/D col=lane&15, row=quad*4+reg (learn_hip m89/m91).
// ---------------------------------------------------------------------------
__global__ __launch_bounds__(256) void gemm_mfma(
    const unsigned short* __restrict__ xb,   // [N,128] bf16
    const unsigned short* __restrict__ wb,   // [512,128] bf16
    unsigned short* __restrict__ u,          // [SL][N][SLC] bf16
    unsigned short* __restrict__ v)          // [SL][N][SLC] bf16
{
    __shared__ unsigned short As[128][C_IN + PAD];
    __shared__ unsigned short Bs[64][C_IN + PAD];
    const int tid = threadIdx.x;

    // Stage A: 128 rows x 128 bf16 (2 threads/row, 8 uint4 each).
    {
        int r = tid >> 1;
        int cb = (tid & 1) * 64;
        int n = blockIdx.x * 128 + r;
        if (n < N_NODES) {
            const uint4* sp = (const uint4*)(xb + (size_t)n * C_IN + cb);
            #pragma unroll
            for (int i = 0; i < 8; ++i) *(uint4*)&As[r][cb + i * 8] = sp[i];
        } else {
            uint4 z = make_uint4(0, 0, 0, 0);
            #pragma unroll
            for (int i = 0; i < 8; ++i) *(uint4*)&As[r][cb + i * 8] = z;
        }
    }
    // Stage B: 64 rows x 128 bf16 (4 threads/row, 4 uint4 each).
    {
        int r = tid >> 2;
        int cb = (tid & 3) * 32;
        const uint4* sp = (const uint4*)(wb + (size_t)(blockIdx.y * 64 + r) * C_IN + cb);
        #pragma unroll
        for (int i = 0; i < 4; ++i) *(uint4*)&Bs[r][cb + i * 8] = sp[i];
    }
    __syncthreads();

    const int wave = tid >> 6;
    const int lane = tid & 63;
    const int l15 = lane & 15;
    const int quad = lane >> 4;

    floatx4 acc[2][4];
    #pragma unroll
    for (int mi = 0; mi < 2; ++mi)
        #pragma unroll
        for (int ni = 0; ni < 4; ++ni)
            acc[mi][ni] = (floatx4){0.f, 0.f, 0.f, 0.f};

    #pragma unroll
    for (int ks = 0; ks < 4; ++ks) {
        short8 a[2], b[4];
        #pragma unroll
        for (int mi = 0; mi < 2; ++mi)
            a[mi] = *(const short8*)&As[wave * 32 + mi * 16 + l15][ks * 32 + quad * 8];
        #pragma unroll
        for (int ni = 0; ni < 4; ++ni)
            b[ni] = *(const short8*)&Bs[ni * 16 + l15][ks * 32 + quad * 8];
        #pragma unroll
        for (int mi = 0; mi < 2; ++mi)
            #pragma unroll
            for (int ni = 0; ni < 4; ++ni)
                acc[mi][ni] = __builtin_amdgcn_mfma_f32_16x16x32_bf16(
                    a[mi], b[ni], acc[mi][ni], 0, 0, 0);
    }

    const bool is_u = (blockIdx.y < 4);   // uniform per block
    #pragma unroll
    for (int mi = 0; mi < 2; ++mi) {
        #pragma unroll
        for (int r = 0; r < 4; ++r) {
            int n = blockIdx.x * 128 + wave * 32 + mi * 16 + quad * 4 + r;
            if (n >= N_NODES) continue;
            #pragma unroll
            for (int ni = 0; ni < 4; ++ni) {
                int c = blockIdx.y * 64 + ni * 16 + l15;   // 0..511
                float val = acc[mi][ni][r];
                if (is_u) {
                    int s = c >> 5, o = c & 31;
                    u[((size_t)s * N_NODES + n) * SLC + o] = f2bf(val);
                } else {
                    int c2 = c - C_OUT;
                    int s = c2 >> 5, o = c2 & 31;
                    v[((size_t)s * N_NODES + n) * SLC + o] = f2bf(val);
                }
            }
        }
    }
}

// ---------------------------------------------------------------------------
// CSR build: histogram -> 3-phase multi-block exclusive scan -> scatter.
// ---------------------------------------------------------------------------
__global__ __launch_bounds__(256) void hist_src(
    const int* __restrict__ src, int* __restrict__ deg)
{
    int i = blockIdx.x * 256 + threadIdx.x;
    if (i < N_EDGES) atomicAdd(&deg[src[i]], 1);
}

__global__ __launch_bounds__(256) void scan_part(
    const int* __restrict__ deg, int* __restrict__ partials)
{
    __shared__ int s[256];
    const int tid = threadIdx.x;
    int i = blockIdx.x * 256 + tid;
    s[tid] = (i < N_NODES) ? deg[i] : 0;
    __syncthreads();
    for (int d = 128; d > 0; d >>= 1) {
        if (tid < d) s[tid] += s[tid + d];
        __syncthreads();
    }
    if (tid == 0) partials[blockIdx.x] = s[0];
}

__global__ __launch_bounds__(256) void scan_mid(
    int* __restrict__ partials, int* __restrict__ off)
{
    __shared__ int s[256];
    const int tid = threadIdx.x;
    int v = (tid < NBLK) ? partials[tid] : 0;
    s[tid] = v;
    __syncthreads();
    for (int d = 1; d < 256; d <<= 1) {
        int t = (tid >= d) ? s[tid - d] : 0;
        __syncthreads();
        s[tid] += t;
        __syncthreads();
    }
    if (tid < NBLK) partials[tid] = s[tid] - v;   // exclusive block prefix
    if (tid == NBLK - 1) off[N_NODES] = s[tid];   // total = E
}

__global__ __launch_bounds__(256) void scan_fin(
    const int* __restrict__ deg, const int* __restrict__ partials,
    int* __restrict__ off, int* __restrict__ cursor)
{
    __shared__ int s[256];
    const int tid = threadIdx.x;
    int i = blockIdx.x * 256 + tid;
    int v = (i < N_NODES) ? deg[i] : 0;
    s[tid] = v;
    __syncthreads();
    for (int d = 1; d < 256; d <<= 1) {
        int t = (tid >= d) ? s[tid - d] : 0;
        __syncthreads();
        s[tid] += t;
        __syncthreads();
    }
    int ex = s[tid] - v + partials[blockIdx.x];
    if (i < N_NODES) { off[i] = ex; cursor[i] = ex; }
}

__global__ __launch_bounds__(256) void scatter_edges(
    const int* __restrict__ src, const int* __restrict__ dst,
    int* __restrict__ cursor, int* __restrict__ edst)
{
    int i = blockIdx.x * 256 + threadIdx.x;
    if (i < N_EDGES) {
        int pos = atomicAdd(&cursor[src[i]], 1);
        edst[pos] = dst[i];
    }
}

// ---------------------------------------------------------------------------
// Sliced gather-max v2. blockIdx & 7 = channel slice = XCD (round-robin
// dispatch): XCD s only touches u-slice s (3.2 MB, its-L2-resident).
// Wave = 32 consecutive nodes; offsets preloaded via lane-load + shfl.
// Inner loop: clamp-free 16-edge body (per-lane ep pointer, imm offsets,
// u-addr = (d<<6)|loff off SGPR base) + one clamped tail; packed bf16 max
// via __hmax2 (1 VALU / 2ch / edge). Cross-group reduce: 2 shfl_xor levels.
// ---------------------------------------------------------------------------
__global__ __launch_bounds__(256) void gather_slice(
    const int* __restrict__ off, const int* __restrict__ edst,
    const unsigned short* __restrict__ u, const unsigned short* __restrict__ v,
    float* __restrict__ out, float* __restrict__ sums, float* __restrict__ sumsq)
{
    const int slice = blockIdx.x & 7;
    const int chunk = blockIdx.x >> 3;
    const int wave = threadIdx.x >> 6;
    const int lane = threadIdx.x & 63;
    const int g = lane >> 4;          // edge group 0..3
    const int l16 = lane & 15;        // channel-pair index within slice
    const int loff = l16 * 4;         // byte offset within 64B u row

    const char* ub = (const char*)(u + (size_t)slice * N_NODES * SLC);
    const unsigned short* vb = v + (size_t)slice * N_NODES * SLC;

    const int nbw = chunk * NPB + wave * 32;   // this wave's first node
    int myoff = 0;
    if (lane <= 32) myoff = off[min(nbw + lane, N_NODES)];

    float s1_0 = 0.f, s1_1 = 0.f, s2_0 = 0.f, s2_1 = 0.f;

    for (int i = 0; i < 32; ++i) {
        const int n = nbw + i;
        if (n >= N_NODES) break;
        const int start = __shfl(myoff, i);
        const int end = __shfl(myoff, i + 1);
        float a0 = 0.f, a1 = 0.f;
        if (end > start) {
            UB2 m; m.u = 0xFF80FF80u;           // packed bf16 -inf
            const int* ep = edst + start + g;
            const int nfull = (end - start) >> 4;
            for (int it = 0; it < nfull; ++it) {
                int d0 = ep[0], d1 = ep[4], d2 = ep[8], d3 = ep[12];
                UB2 w0, w1, w2, w3;
                w0.u = *(const unsigned int*)(ub + ((d0 << 6) | loff));
                w1.u = *(const unsigned int*)(ub + ((d1 << 6) | loff));
                w2.u = *(const unsigned int*)(ub + ((d2 << 6) | loff));
                w3.u = *(const unsigned int*)(ub + ((d3 << 6) | loff));
                m.b = __hmax2(m.b, __hmax2(__hmax2(w0.b, w1.b),
                                           __hmax2(w2.b, w3.b)));
                ep += 16;
            }
            int e = start + (nfull << 4);
            if (e < end) {                      // clamped tail (dups ok)
                const int lim = end - 1;
                int i0 = min(e + g, lim),      i1 = min(e + 4 + g, lim);
                int i2 = min(e + 8 + g, lim),  i3 = min(e + 12 + g, lim);
                int d0 = edst[i0], d1 = edst[i1], d2 = edst[i2], d3 = edst[i3];
                UB2 w0, w1, w2, w3;
                w0.u = *(const unsigned int*)(ub + ((d0 << 6) | loff));
                w1.u = *(const unsigned int*)(ub + ((d1 << 6) | loff));
                w2.u = *(const unsigned int*)(ub + ((d2 << 6) | loff));
                w3.u = *(const unsigned int*)(ub + ((d3 << 6) | loff));
                m.b = __hmax2(m.b, __hmax2(__hmax2(w0.b, w1.b),
                                           __hmax2(w2.b, w3.b)));
            }
            // reduce across the 4 edge groups
            UB2 o1; o1.u = (unsigned int)__shfl_xor((int)m.u, 16);
            m.b = __hmax2(m.b, o1.b);
            UB2 o2; o2.u = (unsigned int)__shfl_xor((int)m.u, 32);
            m.b = __hmax2(m.b, o2.b);
            unsigned int wv = *(const unsigned int*)(vb + (size_t)n * SLC + l16 * 2);
            a0 = fmaxf(bflo(wv) + bflo(m.u), 0.f);
            a1 = fmaxf(bfhi(wv) + bfhi(m.u), 0.f);
        }
        if (g == 0) {
            *(float2*)(out + (size_t)n * C_OUT + slice * SLC + l16 * 2) =
                make_float2(a0, a1);
            s1_0 += a0; s1_1 += a1;
            s2_0 += a0 * a0; s2_1 += a1 * a1;
        }
    }

    __shared__ float red[4][16][4];
    if (g == 0) {
        red[wave][l16][0] = s1_0; red[wave][l16][1] = s1_1;
        red[wave][l16][2] = s2_0; red[wave][l16][3] = s2_1;
    }
    __syncthreads();
    if (threadIdx.x < 16) {
        const int t = threadIdx.x;
        float r0 = 0.f, r1 = 0.f, r2 = 0.f, r3 = 0.f;
        #pragma unroll
        for (int w = 0; w < 4; ++w) {
            r0 += red[w][t][0]; r1 += red[w][t][1];
            r2 += red[w][t][2]; r3 += red[w][t][3];
        }
        const int c = slice * SLC + t * 2;
        atomicAdd(&sums[c + 0], r0);
        atomicAdd(&sums[c + 1], r1);
        atomicAdd(&sumsq[c + 0], r2);
        atomicAdd(&sumsq[c + 1], r3);
    }
}

// ---------------------------------------------------------------------------
// BN coefficients: y = agg*A[c] + B[c], then relu.
// ---------------------------------------------------------------------------
__global__ __launch_bounds__(256) void bn_prep(
    const float* __restrict__ sums, const float* __restrict__ sumsq,
    const float* __restrict__ gamma, const float* __restrict__ beta,
    float* __restrict__ coefA, float* __restrict__ coefB)
{
    const int c = threadIdx.x;
    const float inv_n = 1.f / (float)N_NODES;
    const float mean = sums[c] * inv_n;
    const float var = sumsq[c] * inv_n - mean * mean;
    const float s = rsqrtf(var + BN_EPS) * gamma[c];
    coefA[c] = s;
    coefB[c] = beta[c] - mean * s;
}

__global__ __launch_bounds__(256) void bn_apply(
    float* __restrict__ out, const float* __restrict__ coefA,
    const float* __restrict__ coefB)
{
    const int i = blockIdx.x * 256 + threadIdx.x;
    if (i >= N_NODES * C_OUT / 4) return;
    const int c4 = (i * 4) & (C_OUT - 1);
    float4 o = ((float4*)out)[i];
    const float4 A = *(const float4*)(coefA + c4);
    const float4 B = *(const float4*)(coefB + c4);
    o.x = fmaxf(o.x * A.x + B.x, 0.f);
    o.y = fmaxf(o.y * A.y + B.y, 0.f);
    o.z = fmaxf(o.z * A.z + B.z, 0.f);
    o.w = fmaxf(o.w * A.w + B.w, 0.f);
    ((float4*)out)[i] = o;
}

extern "C" void kernel_launch(void* const* d_in, const int* in_sizes, int n_in,
                              void* d_out, int out_size, void* d_ws, size_t ws_size,
                              hipStream_t stream) {
    const float* x     = (const float*)d_in[0];
    const int*   src   = (const int*)d_in[1];
    const int*   dst   = (const int*)d_in[2];
    const float* theta = (const float*)d_in[3];
    const float* phi   = (const float*)d_in[4];
    const float* gamma = (const float*)d_in[5];
    const float* beta  = (const float*)d_in[6];
    float* out = (float*)d_out;

    // Workspace layout (16B-aligned chunks):
    char* ws = (char*)d_ws;
    const size_t uv_elems = (size_t)N_NODES * C_OUT;
    unsigned short* u = (unsigned short*)ws;                       // 25.6 MB bf16 slice-major
    unsigned short* v = u + uv_elems;                              // 25.6 MB bf16 slice-major
    float* sums   = (float*)(v + uv_elems);
    float* sumsq  = sums + C_OUT;
    float* coefA  = sumsq + C_OUT;
    float* coefB  = coefA + C_OUT;
    int*   deg    = (int*)(coefB + C_OUT);                         // contiguous for one memset
    int*   off    = deg + N_NODES;                                 // N_NODES+1 entries
    int*   cursor = off + N_NODES + 4;                             // pad keeps 16B align
    int*   edst   = cursor + N_NODES;                              // 3.2 MB
    int*   partials = edst + N_EDGES;                              // NBLK ints
    unsigned short* xb = (unsigned short*)(partials + NBLK + 8);   // 12.8 MB bf16
    unsigned short* wb = xb + (size_t)N_NODES * C_IN;              // 128 KB bf16

    // Zero sums/sumsq/coefs/deg in one shot (contiguous).
    hipMemsetAsync(sums, 0, (4 * C_OUT + N_NODES) * sizeof(int), stream);

    convert_x<<<(N_NODES * C_IN / 4 + 255) / 256, 256, 0, stream>>>(x, xb);
    convert_w<<<(512 * C_IN / 4 + 255) / 256, 256, 0, stream>>>(theta, phi, wb);

    dim3 gA((N_NODES + 127) / 128, 8);
    gemm_mfma<<<gA, 256, 0, stream>>>(xb, wb, u, v);

    const int EB = (N_EDGES + 255) / 256;
    hist_src<<<EB, 256, 0, stream>>>(src, deg);
    scan_part<<<NBLK, 256, 0, stream>>>(deg, partials);
    scan_mid<<<1, 256, 0, stream>>>(partials, off);
    scan_fin<<<NBLK, 256, 0, stream>>>(deg, partials, off, cursor);
    scatter_edges<<<EB, 256, 0, stream>>>(src, dst, cursor, edst);

    const int chunks = (N_NODES + NPB - 1) / NPB;
    gather_slice<<<chunks * SL, 256, 0, stream>>>(
        off, edst, u, v, out, sums, sumsq);

    bn_prep<<<1, 256, 0, stream>>>(sums, sumsq, gamma, beta, coefA, coefB);
    bn_apply<<<(N_NODES * C_OUT / 4 + 255) / 256, 256, 0, stream>>>(
        out, coefA, coefB);
}

// Round 7
// 301.484 us; speedup vs baseline: 1.5315x; 1.5315x over previous
//
#include <hip/hip_runtime.h>

#define N_NODES 50000
#define N_EDGES 800000
#define C_IN 128
#define C_OUT 256
#define BN_EPS 1e-5f
#define NBLK ((N_NODES + 255) / 256)   // 196 scan blocks
#define SL 8                           // channel slices (== XCD count)
#define SLC 32                         // channels per slice
#define NPB 128                        // nodes per gather block (8 per 16-lane group)
#define PAD 8                          // LDS row pad (bf16 elems, keeps 16B align)

using short8  = __attribute__((ext_vector_type(8))) short;
using floatx4 = __attribute__((ext_vector_type(4))) float;

// fp32 -> bf16 round-to-nearest-even
__device__ __forceinline__ unsigned short f2bf(float f) {
    unsigned int u = __float_as_uint(f);
    u = (u + 0x7fffu + ((u >> 16) & 1u)) >> 16;
    return (unsigned short)u;
}
__device__ __forceinline__ float bflo(unsigned int w) {
    return __uint_as_float(w << 16);
}
__device__ __forceinline__ float bfhi(unsigned int w) {
    return __uint_as_float(w & 0xFFFF0000u);
}

// ---------------------------------------------------------------------------
// Converts: x -> bf16 [N,128]; W' = [theta ; phi-theta] -> bf16 [512,128].
// Identity: theta@(xj-xi) + phi@xi = u[dst] + v[src]; relu/max commute so the
// edge pass only needs max over u rows.
// ---------------------------------------------------------------------------
__global__ __launch_bounds__(256) void convert_x(
    const float* __restrict__ x, unsigned short* __restrict__ xb)
{
    int i = blockIdx.x * 256 + threadIdx.x;
    if (i < N_NODES * C_IN / 4) {
        float4 vv = ((const float4*)x)[i];
        ((ushort4*)xb)[i] = make_ushort4(f2bf(vv.x), f2bf(vv.y),
                                         f2bf(vv.z), f2bf(vv.w));
    }
}

__global__ __launch_bounds__(256) void convert_w(
    const float* __restrict__ theta, const float* __restrict__ phi,
    unsigned short* __restrict__ wb)
{
    int i = blockIdx.x * 256 + threadIdx.x;       // float4 index over [512][128]
    if (i >= 512 * C_IN / 4) return;
    float4 t;
    if (i < 256 * C_IN / 4) {
        t = ((const float4*)theta)[i];
    } else {
        int j = i - 256 * C_IN / 4;
        float4 th = ((const float4*)theta)[j];
        float4 ph = ((const float4*)phi)[j];
        t = make_float4(ph.x - th.x, ph.y - th.y, ph.z - th.z, ph.w - th.w);
    }
    ((ushort4*)wb)[i] = make_ushort4(f2bf(t.x), f2bf(t.y), f2bf(t.z), f2bf(t.w));
}

// ---------------------------------------------------------------------------
// MFMA GEMM: M=50000, N=512, K=128. Block tile 128x64, K fully staged.
// Outputs slice-major u (bf16) / v (bf16) for the XCD-local gather.
// Verified layouts: A-frag A[m=lane&15][k=quad*8+j]; B-frag B[k][n=lane&15];
// C/D col=lane&15, row=quad*4+reg (learn_hip m89/m91).
// ---------------------------------------------------------------------------
__global__ __launch_bounds__(256) void gemm_mfma(
    const unsigned short* __restrict__ xb,   // [N,128] bf16
    const unsigned short* __restrict__ wb,   // [512,128] bf16
    unsigned short* __restrict__ u,          // [SL][N][SLC] bf16
    unsigned short* __restrict__ v)          // [SL][N][SLC] bf16
{
    __shared__ unsigned short As[128][C_IN + PAD];
    __shared__ unsigned short Bs[64][C_IN + PAD];
    const int tid = threadIdx.x;

    // Stage A: 128 rows x 128 bf16 (2 threads/row, 8 uint4 each).
    {
        int r = tid >> 1;
        int cb = (tid & 1) * 64;
        int n = blockIdx.x * 128 + r;
        if (n < N_NODES) {
            const uint4* sp = (const uint4*)(xb + (size_t)n * C_IN + cb);
            #pragma unroll
            for (int i = 0; i < 8; ++i) *(uint4*)&As[r][cb + i * 8] = sp[i];
        } else {
            uint4 z = make_uint4(0, 0, 0, 0);
            #pragma unroll
            for (int i = 0; i < 8; ++i) *(uint4*)&As[r][cb + i * 8] = z;
        }
    }
    // Stage B: 64 rows x 128 bf16 (4 threads/row, 4 uint4 each).
    {
        int r = tid >> 2;
        int cb = (tid & 3) * 32;
        const uint4* sp = (const uint4*)(wb + (size_t)(blockIdx.y * 64 + r) * C_IN + cb);
        #pragma unroll
        for (int i = 0; i < 4; ++i) *(uint4*)&Bs[r][cb + i * 8] = sp[i];
    }
    __syncthreads();

    const int wave = tid >> 6;
    const int lane = tid & 63;
    const int l15 = lane & 15;
    const int quad = lane >> 4;

    floatx4 acc[2][4];
    #pragma unroll
    for (int mi = 0; mi < 2; ++mi)
        #pragma unroll
        for (int ni = 0; ni < 4; ++ni)
            acc[mi][ni] = (floatx4){0.f, 0.f, 0.f, 0.f};

    #pragma unroll
    for (int ks = 0; ks < 4; ++ks) {
        short8 a[2], b[4];
        #pragma unroll
        for (int mi = 0; mi < 2; ++mi)
            a[mi] = *(const short8*)&As[wave * 32 + mi * 16 + l15][ks * 32 + quad * 8];
        #pragma unroll
        for (int ni = 0; ni < 4; ++ni)
            b[ni] = *(const short8*)&Bs[ni * 16 + l15][ks * 32 + quad * 8];
        #pragma unroll
        for (int mi = 0; mi < 2; ++mi)
            #pragma unroll
            for (int ni = 0; ni < 4; ++ni)
                acc[mi][ni] = __builtin_amdgcn_mfma_f32_16x16x32_bf16(
                    a[mi], b[ni], acc[mi][ni], 0, 0, 0);
    }

    const bool is_u = (blockIdx.y < 4);   // uniform per block
    #pragma unroll
    for (int mi = 0; mi < 2; ++mi) {
        #pragma unroll
        for (int r = 0; r < 4; ++r) {
            int n = blockIdx.x * 128 + wave * 32 + mi * 16 + quad * 4 + r;
            if (n >= N_NODES) continue;
            #pragma unroll
            for (int ni = 0; ni < 4; ++ni) {
                int c = blockIdx.y * 64 + ni * 16 + l15;   // 0..511
                float val = acc[mi][ni][r];
                if (is_u) {
                    int s = c >> 5, o = c & 31;
                    u[((size_t)s * N_NODES + n) * SLC + o] = f2bf(val);
                } else {
                    int c2 = c - C_OUT;
                    int s = c2 >> 5, o = c2 & 31;
                    v[((size_t)s * N_NODES + n) * SLC + o] = f2bf(val);
                }
            }
        }
    }
}

// ---------------------------------------------------------------------------
// CSR build: histogram -> 3-phase multi-block exclusive scan -> scatter.
// ---------------------------------------------------------------------------
__global__ __launch_bounds__(256) void hist_src(
    const int* __restrict__ src, int* __restrict__ deg)
{
    int i = blockIdx.x * 256 + threadIdx.x;
    if (i < N_EDGES) atomicAdd(&deg[src[i]], 1);
}

__global__ __launch_bounds__(256) void scan_part(
    const int* __restrict__ deg, int* __restrict__ partials)
{
    __shared__ int s[256];
    const int tid = threadIdx.x;
    int i = blockIdx.x * 256 + tid;
    s[tid] = (i < N_NODES) ? deg[i] : 0;
    __syncthreads();
    for (int d = 128; d > 0; d >>= 1) {
        if (tid < d) s[tid] += s[tid + d];
        __syncthreads();
    }
    if (tid == 0) partials[blockIdx.x] = s[0];
}

__global__ __launch_bounds__(256) void scan_mid(
    int* __restrict__ partials, int* __restrict__ off)
{
    __shared__ int s[256];
    const int tid = threadIdx.x;
    int v = (tid < NBLK) ? partials[tid] : 0;
    s[tid] = v;
    __syncthreads();
    for (int d = 1; d < 256; d <<= 1) {
        int t = (tid >= d) ? s[tid - d] : 0;
        __syncthreads();
        s[tid] += t;
        __syncthreads();
    }
    if (tid < NBLK) partials[tid] = s[tid] - v;   // exclusive block prefix
    if (tid == NBLK - 1) off[N_NODES] = s[tid];   // total = E
}

__global__ __launch_bounds__(256) void scan_fin(
    const int* __restrict__ deg, const int* __restrict__ partials,
    int* __restrict__ off, int* __restrict__ cursor)
{
    __shared__ int s[256];
    const int tid = threadIdx.x;
    int i = blockIdx.x * 256 + tid;
    int v = (i < N_NODES) ? deg[i] : 0;
    s[tid] = v;
    __syncthreads();
    for (int d = 1; d < 256; d <<= 1) {
        int t = (tid >= d) ? s[tid - d] : 0;
        __syncthreads();
        s[tid] += t;
        __syncthreads();
    }
    int ex = s[tid] - v + partials[blockIdx.x];
    if (i < N_NODES) { off[i] = ex; cursor[i] = ex; }
}

__global__ __launch_bounds__(256) void scatter_edges(
    const int* __restrict__ src, const int* __restrict__ dst,
    int* __restrict__ cursor, int* __restrict__ edst)
{
    int i = blockIdx.x * 256 + threadIdx.x;
    if (i < N_EDGES) {
        int pos = atomicAdd(&cursor[src[i]], 1);
        edst[pos] = dst[i];
    }
}

// ---------------------------------------------------------------------------
// Sliced gather-max v3. blockIdx & 7 = channel slice = XCD (round-robin
// dispatch): XCD s only touches u-slice s (3.2 MB, its-L2-resident).
// ONE NODE PER 16-LANE GROUP (16 lanes = 16 ch-pairs = whole slice):
// 4 independent nodes per wave, no cross-lane reduce. Inner loop 8 edges
// deep -> 8 independent u loads + 2 dwordx4 edst loads in flight per group
// (~32-64 outstanding per wave) to hide L2 latency. Tail: one clamped
// 8-load block (duplicate loads are L1 hits, harmless under max).
// Max arithmetic: shift/mask unpack + v_max_f32 (v_max3-foldable) — NOT
// __hmax2, which gfx950 emulates in ~10 VALU ops (R6 regression).
// ---------------------------------------------------------------------------
__global__ __launch_bounds__(256) void gather_slice(
    const int* __restrict__ off, const int* __restrict__ edst,
    const unsigned short* __restrict__ u, const unsigned short* __restrict__ v,
    float* __restrict__ out, float* __restrict__ sums, float* __restrict__ sumsq)
{
    const int slice = blockIdx.x & 7;
    const int chunk = blockIdx.x >> 3;
    const int wave = threadIdx.x >> 6;
    const int lane = threadIdx.x & 63;
    const int grp = lane >> 4;        // node sub-group 0..3
    const int l16 = lane & 15;        // channel-pair index within slice
    const int loff = l16 * 4;         // byte offset within 64B u row
    const int g16 = wave * 4 + grp;   // block-level group id 0..15

    const char* ub = (const char*)(u + (size_t)slice * N_NODES * SLC);
    const unsigned short* vb = v + (size_t)slice * N_NODES * SLC;

    float s1_0 = 0.f, s1_1 = 0.f, s2_0 = 0.f, s2_1 = 0.f;

    #pragma unroll 1
    for (int i = 0; i < NPB / 16; ++i) {
        const int n = chunk * NPB + i * 16 + g16;
        if (n >= N_NODES) continue;
        const int start = off[n];
        const int end = off[n + 1];
        float a0 = 0.f, a1 = 0.f;
        if (end > start) {
            float m0 = -INFINITY, m1 = -INFINITY;
            const int nfull = (end - start) >> 3;
            const int* ep = edst + start;
            for (int it = 0; it < nfull; ++it) {
                int d0 = ep[0], d1 = ep[1], d2 = ep[2], d3 = ep[3];
                int d4 = ep[4], d5 = ep[5], d6 = ep[6], d7 = ep[7];
                unsigned int w0 = *(const unsigned int*)(ub + ((d0 << 6) | loff));
                unsigned int w1 = *(const unsigned int*)(ub + ((d1 << 6) | loff));
                unsigned int w2 = *(const unsigned int*)(ub + ((d2 << 6) | loff));
                unsigned int w3 = *(const unsigned int*)(ub + ((d3 << 6) | loff));
                unsigned int w4 = *(const unsigned int*)(ub + ((d4 << 6) | loff));
                unsigned int w5 = *(const unsigned int*)(ub + ((d5 << 6) | loff));
                unsigned int w6 = *(const unsigned int*)(ub + ((d6 << 6) | loff));
                unsigned int w7 = *(const unsigned int*)(ub + ((d7 << 6) | loff));
                m0 = fmaxf(m0, fmaxf(fmaxf(fmaxf(bflo(w0), bflo(w1)), fmaxf(bflo(w2), bflo(w3))),
                                     fmaxf(fmaxf(bflo(w4), bflo(w5)), fmaxf(bflo(w6), bflo(w7)))));
                m1 = fmaxf(m1, fmaxf(fmaxf(fmaxf(bfhi(w0), bfhi(w1)), fmaxf(bfhi(w2), bfhi(w3))),
                                     fmaxf(fmaxf(bfhi(w4), bfhi(w5)), fmaxf(bfhi(w6), bfhi(w7)))));
                ep += 8;
            }
            const int base = start + (nfull << 3);
            if (base < end) {                 // clamped tail (dups ok under max)
                const int lim = end - 1;
                int d0 = edst[base];
                int d1 = edst[min(base + 1, lim)], d2 = edst[min(base + 2, lim)];
                int d3 = edst[min(base + 3, lim)], d4 = edst[min(base + 4, lim)];
                int d5 = edst[min(base + 5, lim)], d6 = edst[min(base + 6, lim)];
                int d7 = edst[min(base + 7, lim)];
                unsigned int w0 = *(const unsigned int*)(ub + ((d0 << 6) | loff));
                unsigned int w1 = *(const unsigned int*)(ub + ((d1 << 6) | loff));
                unsigned int w2 = *(const unsigned int*)(ub + ((d2 << 6) | loff));
                unsigned int w3 = *(const unsigned int*)(ub + ((d3 << 6) | loff));
                unsigned int w4 = *(const unsigned int*)(ub + ((d4 << 6) | loff));
                unsigned int w5 = *(const unsigned int*)(ub + ((d5 << 6) | loff));
                unsigned int w6 = *(const unsigned int*)(ub + ((d6 << 6) | loff));
                unsigned int w7 = *(const unsigned int*)(ub + ((d7 << 6) | loff));
                m0 = fmaxf(m0, fmaxf(fmaxf(fmaxf(bflo(w0), bflo(w1)), fmaxf(bflo(w2), bflo(w3))),
                                     fmaxf(fmaxf(bflo(w4), bflo(w5)), fmaxf(bflo(w6), bflo(w7)))));
                m1 = fmaxf(m1, fmaxf(fmaxf(fmaxf(bfhi(w0), bfhi(w1)), fmaxf(bfhi(w2), bfhi(w3))),
                                     fmaxf(fmaxf(bfhi(w4), bfhi(w5)), fmaxf(bfhi(w6), bfhi(w7)))));
            }
            unsigned int wv = *(const unsigned int*)(vb + (size_t)n * SLC + l16 * 2);
            a0 = fmaxf(bflo(wv) + m0, 0.f);
            a1 = fmaxf(bfhi(wv) + m1, 0.f);
        }
        *(float2*)(out + (size_t)n * C_OUT + slice * SLC + l16 * 2) =
            make_float2(a0, a1);
        s1_0 += a0; s1_1 += a1;
        s2_0 += a0 * a0; s2_1 += a1 * a1;
    }

    // Stats: reduce across the 16 groups; channels are disjoint per l16.
    __shared__ float red[16][16][4];
    red[g16][l16][0] = s1_0; red[g16][l16][1] = s1_1;
    red[g16][l16][2] = s2_0; red[g16][l16][3] = s2_1;
    __syncthreads();
    if (threadIdx.x < 16) {
        const int t = threadIdx.x;
        float r0 = 0.f, r1 = 0.f, r2 = 0.f, r3 = 0.f;
        #pragma unroll
        for (int g = 0; g < 16; ++g) {
            r0 += red[g][t][0]; r1 += red[g][t][1];
            r2 += red[g][t][2]; r3 += red[g][t][3];
        }
        const int c = slice * SLC + t * 2;
        atomicAdd(&sums[c + 0], r0);
        atomicAdd(&sums[c + 1], r1);
        atomicAdd(&sumsq[c + 0], r2);
        atomicAdd(&sumsq[c + 1], r3);
    }
}

// ---------------------------------------------------------------------------
// BN coefficients: y = agg*A[c] + B[c], then relu.
// ---------------------------------------------------------------------------
__global__ __launch_bounds__(256) void bn_prep(
    const float* __restrict__ sums, const float* __restrict__ sumsq,
    const float* __restrict__ gamma, const float* __restrict__ beta,
    float* __restrict__ coefA, float* __restrict__ coefB)
{
    const int c = threadIdx.x;
    const float inv_n = 1.f / (float)N_NODES;
    const float mean = sums[c] * inv_n;
    const float var = sumsq[c] * inv_n - mean * mean;
    const float s = rsqrtf(var + BN_EPS) * gamma[c];
    coefA[c] = s;
    coefB[c] = beta[c] - mean * s;
}

__global__ __launch_bounds__(256) void bn_apply(
    float* __restrict__ out, const float* __restrict__ coefA,
    const float* __restrict__ coefB)
{
    const int i = blockIdx.x * 256 + threadIdx.x;
    if (i >= N_NODES * C_OUT / 4) return;
    const int c4 = (i * 4) & (C_OUT - 1);
    float4 o = ((float4*)out)[i];
    const float4 A = *(const float4*)(coefA + c4);
    const float4 B = *(const float4*)(coefB + c4);
    o.x = fmaxf(o.x * A.x + B.x, 0.f);
    o.y = fmaxf(o.y * A.y + B.y, 0.f);
    o.z = fmaxf(o.z * A.z + B.z, 0.f);
    o.w = fmaxf(o.w * A.w + B.w, 0.f);
    ((float4*)out)[i] = o;
}

extern "C" void kernel_launch(void* const* d_in, const int* in_sizes, int n_in,
                              void* d_out, int out_size, void* d_ws, size_t ws_size,
                              hipStream_t stream) {
    const float* x     = (const float*)d_in[0];
    const int*   src   = (const int*)d_in[1];
    const int*   dst   = (const int*)d_in[2];
    const float* theta = (const float*)d_in[3];
    const float* phi   = (const float*)d_in[4];
    const float* gamma = (const float*)d_in[5];
    const float* beta  = (const float*)d_in[6];
    float* out = (float*)d_out;

    // Workspace layout (16B-aligned chunks):
    char* ws = (char*)d_ws;
    const size_t uv_elems = (size_t)N_NODES * C_OUT;
    unsigned short* u = (unsigned short*)ws;                       // 25.6 MB bf16 slice-major
    unsigned short* v = u + uv_elems;                              // 25.6 MB bf16 slice-major
    float* sums   = (float*)(v + uv_elems);
    float* sumsq  = sums + C_OUT;
    float* coefA  = sumsq + C_OUT;
    float* coefB  = coefA + C_OUT;
    int*   deg    = (int*)(coefB + C_OUT);                         // contiguous for one memset
    int*   off    = deg + N_NODES;                                 // N_NODES+1 entries
    int*   cursor = off + N_NODES + 4;                             // pad keeps 16B align
    int*   edst   = cursor + N_NODES;                              // 3.2 MB
    int*   partials = edst + N_EDGES;                              // NBLK ints
    unsigned short* xb = (unsigned short*)(partials + NBLK + 8);   // 12.8 MB bf16
    unsigned short* wb = xb + (size_t)N_NODES * C_IN;              // 128 KB bf16

    // Zero sums/sumsq/coefs/deg in one shot (contiguous).
    hipMemsetAsync(sums, 0, (4 * C_OUT + N_NODES) * sizeof(int), stream);

    convert_x<<<(N_NODES * C_IN / 4 + 255) / 256, 256, 0, stream>>>(x, xb);
    convert_w<<<(512 * C_IN / 4 + 255) / 256, 256, 0, stream>>>(theta, phi, wb);

    dim3 gA((N_NODES + 127) / 128, 8);
    gemm_mfma<<<gA, 256, 0, stream>>>(xb, wb, u, v);

    const int EB = (N_EDGES + 255) / 256;
    hist_src<<<EB, 256, 0, stream>>>(src, deg);
    scan_part<<<NBLK, 256, 0, stream>>>(deg, partials);
    scan_mid<<<1, 256, 0, stream>>>(partials, off);
    scan_fin<<<NBLK, 256, 0, stream>>>(deg, partials, off, cursor);
    scatter_edges<<<EB, 256, 0, stream>>>(src, dst, cursor, edst);

    const int chunks = (N_NODES + NPB - 1) / NPB;
    gather_slice<<<chunks * SL, 256, 0, stream>>>(
        off, edst, u, v, out, sums, sumsq);

    bn_prep<<<1, 256, 0, stream>>>(sums, sumsq, gamma, beta, coefA, coefB);
    bn_apply<<<(N_NODES * C_OUT / 4 + 255) / 256, 256, 0, stream>>>(
        out, coefA, coefB);
}

// Round 9
// 300.459 us; speedup vs baseline: 1.5368x; 1.0034x over previous
//
#include <hip/hip_runtime.h>

#define N_NODES 50000
#define N_EDGES 800000
#define C_IN 128
#define C_OUT 256
#define BN_EPS 1e-5f
#define NBLK ((N_NODES + 255) / 256)   // 196 scan blocks
#define SL 8                           // channel slices (== XCD count)
#define SLC 32                         // channels per slice
#define NPB 128                        // nodes per gather block (8 per 16-lane group)
#define PAD 8                          // LDS row pad (elems, keeps 16B align)

using short8  = __attribute__((ext_vector_type(8))) short;
using floatx4 = __attribute__((ext_vector_type(4))) float;
using h2      = __attribute__((ext_vector_type(2))) _Float16;

union UH2 { unsigned int u; h2 h; };
union HS  { _Float16 f; unsigned short s; };

// packed f16 max -> v_pk_max_f16 (no header dependency; ROCm 7.2 lacks __hmax2)
__device__ __forceinline__ h2 pkmax(h2 a, h2 b) {
    return __builtin_elementwise_max(a, b);
}

// fp32 -> bf16 round-to-nearest-even (GEMM inputs only)
__device__ __forceinline__ unsigned short f2bf(float f) {
    unsigned int u = __float_as_uint(f);
    u = (u + 0x7fffu + ((u >> 16) & 1u)) >> 16;
    return (unsigned short)u;
}

// ---------------------------------------------------------------------------
// Convert x -> bf16 [N,128] and W' = [theta ; phi-theta] -> bf16 [512,128].
// Identity: theta@(xj-xi) + phi@xi = u[dst] + v[src]; relu/max commute so the
// edge pass only needs max over u rows.
// ---------------------------------------------------------------------------
#define XQ (N_NODES * C_IN / 4)        // 1,600,000 float4 of x
#define WQ (512 * C_IN / 4)            // 16,384 float4 of W'

__global__ __launch_bounds__(256) void convert_xw(
    const float* __restrict__ x, const float* __restrict__ theta,
    const float* __restrict__ phi, unsigned short* __restrict__ xb,
    unsigned short* __restrict__ wb)
{
    int i = blockIdx.x * 256 + threadIdx.x;
    if (i < XQ) {
        float4 vv = ((const float4*)x)[i];
        ((ushort4*)xb)[i] = make_ushort4(f2bf(vv.x), f2bf(vv.y),
                                         f2bf(vv.z), f2bf(vv.w));
    } else if (i < XQ + WQ) {
        int j = i - XQ;
        float4 t;
        if (j < 256 * C_IN / 4) {
            t = ((const float4*)theta)[j];
        } else {
            int k = j - 256 * C_IN / 4;
            float4 th = ((const float4*)theta)[k];
            float4 ph = ((const float4*)phi)[k];
            t = make_float4(ph.x - th.x, ph.y - th.y, ph.z - th.z, ph.w - th.w);
        }
        ((ushort4*)wb)[j] = make_ushort4(f2bf(t.x), f2bf(t.y),
                                         f2bf(t.z), f2bf(t.w));
    }
}

// ---------------------------------------------------------------------------
// MFMA GEMM: M=50000, N=512, K=128. Block tile 128x128 (y=4 -> xb fetched
// 4x = 51 MB, half of the 64-col tile). K fully staged in LDS (70 KB).
// Outputs slice-major u/v in FP16 (native v_pk_max_f16 in the gather).
// Verified layouts: A-frag A[m=lane&15][k=quad*8+j]; B-frag B[k][n=lane&15];
// C/D col=lane&15, row=quad*4+reg (learn_hip m89/m91).
// ---------------------------------------------------------------------------
__global__ __launch_bounds__(256) void gemm_mfma(
    const unsigned short* __restrict__ xb,   // [N,128] bf16
    const unsigned short* __restrict__ wb,   // [512,128] bf16
    unsigned short* __restrict__ u,          // [SL][N][SLC] fp16
    unsigned short* __restrict__ v)          // [SL][N][SLC] fp16
{
    __shared__ unsigned short As[128][C_IN + PAD];
    __shared__ unsigned short Bs[128][C_IN + PAD];
    const int tid = threadIdx.x;

    // Stage A: 128 rows x 128 bf16 (2 threads/row, 8 uint4 each).
    {
        int r = tid >> 1;
        int cb = (tid & 1) * 64;
        int n = blockIdx.x * 128 + r;
        if (n < N_NODES) {
            const uint4* sp = (const uint4*)(xb + (size_t)n * C_IN + cb);
            #pragma unroll
            for (int i = 0; i < 8; ++i) *(uint4*)&As[r][cb + i * 8] = sp[i];
        } else {
            uint4 z = make_uint4(0, 0, 0, 0);
            #pragma unroll
            for (int i = 0; i < 8; ++i) *(uint4*)&As[r][cb + i * 8] = z;
        }
    }
    // Stage B: 128 rows x 128 bf16 (2 threads/row, 8 uint4 each).
    {
        int r = tid >> 1;
        int cb = (tid & 1) * 64;
        const uint4* sp = (const uint4*)(wb + (size_t)(blockIdx.y * 128 + r) * C_IN + cb);
        #pragma unroll
        for (int i = 0; i < 8; ++i) *(uint4*)&Bs[r][cb + i * 8] = sp[i];
    }
    __syncthreads();

    const int wave = tid >> 6;
    const int lane = tid & 63;
    const int l15 = lane & 15;
    const int quad = lane >> 4;

    floatx4 acc[2][8];
    #pragma unroll
    for (int mi = 0; mi < 2; ++mi)
        #pragma unroll
        for (int ni = 0; ni < 8; ++ni)
            acc[mi][ni] = (floatx4){0.f, 0.f, 0.f, 0.f};

    #pragma unroll
    for (int ks = 0; ks < 4; ++ks) {
        short8 a[2], b[8];
        #pragma unroll
        for (int mi = 0; mi < 2; ++mi)
            a[mi] = *(const short8*)&As[wave * 32 + mi * 16 + l15][ks * 32 + quad * 8];
        #pragma unroll
        for (int ni = 0; ni < 8; ++ni)
            b[ni] = *(const short8*)&Bs[ni * 16 + l15][ks * 32 + quad * 8];
        #pragma unroll
        for (int mi = 0; mi < 2; ++mi)
            #pragma unroll
            for (int ni = 0; ni < 8; ++ni)
                acc[mi][ni] = __builtin_amdgcn_mfma_f32_16x16x32_bf16(
                    a[mi], b[ni], acc[mi][ni], 0, 0, 0);
    }

    const bool is_u = (blockIdx.y < 2);   // 128-col tile never straddles 256
    #pragma unroll
    for (int mi = 0; mi < 2; ++mi) {
        #pragma unroll
        for (int r = 0; r < 4; ++r) {
            int n = blockIdx.x * 128 + wave * 32 + mi * 16 + quad * 4 + r;
            if (n >= N_NODES) continue;
            #pragma unroll
            for (int ni = 0; ni < 8; ++ni) {
                int c = blockIdx.y * 128 + ni * 16 + l15;   // 0..511
                HS hv; hv.f = (_Float16)acc[mi][ni][r];
                if (is_u) {
                    int s = c >> 5, o = c & 31;
                    u[((size_t)s * N_NODES + n) * SLC + o] = hv.s;
                } else {
                    int c2 = c - C_OUT;
                    int s = c2 >> 5, o = c2 & 31;
                    v[((size_t)s * N_NODES + n) * SLC + o] = hv.s;
                }
            }
        }
    }
}

// ---------------------------------------------------------------------------
// CSR build: histogram -> 3-phase multi-block exclusive scan -> scatter.
// ---------------------------------------------------------------------------
__global__ __launch_bounds__(256) void hist_src(
    const int* __restrict__ src, int* __restrict__ deg)
{
    int i = blockIdx.x * 256 + threadIdx.x;
    if (i < N_EDGES) atomicAdd(&deg[src[i]], 1);
}

__global__ __launch_bounds__(256) void scan_part(
    const int* __restrict__ deg, int* __restrict__ partials)
{
    __shared__ int s[256];
    const int tid = threadIdx.x;
    int i = blockIdx.x * 256 + tid;
    s[tid] = (i < N_NODES) ? deg[i] : 0;
    __syncthreads();
    for (int d = 128; d > 0; d >>= 1) {
        if (tid < d) s[tid] += s[tid + d];
        __syncthreads();
    }
    if (tid == 0) partials[blockIdx.x] = s[0];
}

__global__ __launch_bounds__(256) void scan_mid(
    int* __restrict__ partials, int* __restrict__ off)
{
    __shared__ int s[256];
    const int tid = threadIdx.x;
    int v = (tid < NBLK) ? partials[tid] : 0;
    s[tid] = v;
    __syncthreads();
    for (int d = 1; d < 256; d <<= 1) {
        int t = (tid >= d) ? s[tid - d] : 0;
        __syncthreads();
        s[tid] += t;
        __syncthreads();
    }
    if (tid < NBLK) partials[tid] = s[tid] - v;   // exclusive block prefix
    if (tid == NBLK - 1) off[N_NODES] = s[tid];   // total = E
}

__global__ __launch_bounds__(256) void scan_fin(
    const int* __restrict__ deg, const int* __restrict__ partials,
    int* __restrict__ off, int* __restrict__ cursor)
{
    __shared__ int s[256];
    const int tid = threadIdx.x;
    int i = blockIdx.x * 256 + tid;
    int v = (i < N_NODES) ? deg[i] : 0;
    s[tid] = v;
    __syncthreads();
    for (int d = 1; d < 256; d <<= 1) {
        int t = (tid >= d) ? s[tid - d] : 0;
        __syncthreads();
        s[tid] += t;
        __syncthreads();
    }
    int ex = s[tid] - v + partials[blockIdx.x];
    if (i < N_NODES) { off[i] = ex; cursor[i] = ex; }
}

__global__ __launch_bounds__(256) void scatter_edges(
    const int* __restrict__ src, const int* __restrict__ dst,
    int* __restrict__ cursor, int* __restrict__ edst)
{
    int i = blockIdx.x * 256 + threadIdx.x;
    if (i < N_EDGES) {
        int pos = atomicAdd(&cursor[src[i]], 1);
        edst[pos] = dst[i];
    }
}

// ---------------------------------------------------------------------------
// Sliced gather-max v4. blockIdx & 7 = channel slice = XCD: XCD s only
// touches u-slice s (3.2 MB, its-L2-resident). One node per 16-lane group
// (16 ch-pairs = whole slice), 8-deep edge unroll for MLP.
// u/v are FP16: pkmax -> native v_pk_max_f16 (1 VALU / 2ch / edge) — unlike
// bf16 __hmax2 which is emulated (~10 VALU, R6 regression).
// ---------------------------------------------------------------------------
__global__ __launch_bounds__(256) void gather_slice(
    const int* __restrict__ off, const int* __restrict__ edst,
    const unsigned short* __restrict__ u, const unsigned short* __restrict__ v,
    float* __restrict__ out, float* __restrict__ sums, float* __restrict__ sumsq)
{
    const int slice = blockIdx.x & 7;
    const int chunk = blockIdx.x >> 3;
    const int wave = threadIdx.x >> 6;
    const int lane = threadIdx.x & 63;
    const int grp = lane >> 4;        // node sub-group 0..3
    const int l16 = lane & 15;        // channel-pair index within slice
    const int loff = l16 * 4;         // byte offset within 64B u row
    const int g16 = wave * 4 + grp;   // block-level group id 0..15

    const char* ub = (const char*)(u + (size_t)slice * N_NODES * SLC);
    const unsigned short* vb = v + (size_t)slice * N_NODES * SLC;

    float s1_0 = 0.f, s1_1 = 0.f, s2_0 = 0.f, s2_1 = 0.f;

    #pragma unroll 1
    for (int i = 0; i < NPB / 16; ++i) {
        const int n = chunk * NPB + i * 16 + g16;
        if (n >= N_NODES) continue;
        const int start = off[n];
        const int end = off[n + 1];
        float a0 = 0.f, a1 = 0.f;
        if (end > start) {
            UH2 m; m.u = 0xFC00FC00u;           // packed f16 -inf
            const int nfull = (end - start) >> 3;
            const int* ep = edst + start;
            for (int it = 0; it < nfull; ++it) {
                int d0 = ep[0], d1 = ep[1], d2 = ep[2], d3 = ep[3];
                int d4 = ep[4], d5 = ep[5], d6 = ep[6], d7 = ep[7];
                UH2 w0, w1, w2, w3, w4, w5, w6, w7;
                w0.u = *(const unsigned int*)(ub + ((d0 << 6) | loff));
                w1.u = *(const unsigned int*)(ub + ((d1 << 6) | loff));
                w2.u = *(const unsigned int*)(ub + ((d2 << 6) | loff));
                w3.u = *(const unsigned int*)(ub + ((d3 << 6) | loff));
                w4.u = *(const unsigned int*)(ub + ((d4 << 6) | loff));
                w5.u = *(const unsigned int*)(ub + ((d5 << 6) | loff));
                w6.u = *(const unsigned int*)(ub + ((d6 << 6) | loff));
                w7.u = *(const unsigned int*)(ub + ((d7 << 6) | loff));
                h2 t0 = pkmax(pkmax(w0.h, w1.h), pkmax(w2.h, w3.h));
                h2 t1 = pkmax(pkmax(w4.h, w5.h), pkmax(w6.h, w7.h));
                m.h = pkmax(m.h, pkmax(t0, t1));
                ep += 8;
            }
            const int base = start + (nfull << 3);
            if (base < end) {                 // clamped tail (dups ok under max)
                const int lim = end - 1;
                int d0 = edst[base];
                int d1 = edst[min(base + 1, lim)], d2 = edst[min(base + 2, lim)];
                int d3 = edst[min(base + 3, lim)], d4 = edst[min(base + 4, lim)];
                int d5 = edst[min(base + 5, lim)], d6 = edst[min(base + 6, lim)];
                int d7 = edst[min(base + 7, lim)];
                UH2 w0, w1, w2, w3, w4, w5, w6, w7;
                w0.u = *(const unsigned int*)(ub + ((d0 << 6) | loff));
                w1.u = *(const unsigned int*)(ub + ((d1 << 6) | loff));
                w2.u = *(const unsigned int*)(ub + ((d2 << 6) | loff));
                w3.u = *(const unsigned int*)(ub + ((d3 << 6) | loff));
                w4.u = *(const unsigned int*)(ub + ((d4 << 6) | loff));
                w5.u = *(const unsigned int*)(ub + ((d5 << 6) | loff));
                w6.u = *(const unsigned int*)(ub + ((d6 << 6) | loff));
                w7.u = *(const unsigned int*)(ub + ((d7 << 6) | loff));
                h2 t0 = pkmax(pkmax(w0.h, w1.h), pkmax(w2.h, w3.h));
                h2 t1 = pkmax(pkmax(w4.h, w5.h), pkmax(w6.h, w7.h));
                m.h = pkmax(m.h, pkmax(t0, t1));
            }
            UH2 wv; wv.u = *(const unsigned int*)(vb + (size_t)n * SLC + l16 * 2);
            a0 = fmaxf((float)wv.h[0] + (float)m.h[0], 0.f);
            a1 = fmaxf((float)wv.h[1] + (float)m.h[1], 0.f);
        }
        *(float2*)(out + (size_t)n * C_OUT + slice * SLC + l16 * 2) =
            make_float2(a0, a1);
        s1_0 += a0; s1_1 += a1;
        s2_0 += a0 * a0; s2_1 += a1 * a1;
    }

    // Stats: reduce across the 16 groups; channels are disjoint per l16.
    __shared__ float red[16][16][4];
    red[g16][l16][0] = s1_0; red[g16][l16][1] = s1_1;
    red[g16][l16][2] = s2_0; red[g16][l16][3] = s2_1;
    __syncthreads();
    if (threadIdx.x < 16) {
        const int t = threadIdx.x;
        float r0 = 0.f, r1 = 0.f, r2 = 0.f, r3 = 0.f;
        #pragma unroll
        for (int g = 0; g < 16; ++g) {
            r0 += red[g][t][0]; r1 += red[g][t][1];
            r2 += red[g][t][2]; r3 += red[g][t][3];
        }
        const int c = slice * SLC + t * 2;
        atomicAdd(&sums[c + 0], r0);
        atomicAdd(&sums[c + 1], r1);
        atomicAdd(&sumsq[c + 0], r2);
        atomicAdd(&sumsq[c + 1], r3);
    }
}

// ---------------------------------------------------------------------------
// BN coefficients: y = agg*A[c] + B[c], then relu.
// ---------------------------------------------------------------------------
__global__ __launch_bounds__(256) void bn_prep(
    const float* __restrict__ sums, const float* __restrict__ sumsq,
    const float* __restrict__ gamma, const float* __restrict__ beta,
    float* __restrict__ coefA, float* __restrict__ coefB)
{
    const int c = threadIdx.x;
    const float inv_n = 1.f / (float)N_NODES;
    const float mean = sums[c] * inv_n;
    const float var = sumsq[c] * inv_n - mean * mean;
    const float s = rsqrtf(var + BN_EPS) * gamma[c];
    coefA[c] = s;
    coefB[c] = beta[c] - mean * s;
}

__global__ __launch_bounds__(256) void bn_apply(
    float* __restrict__ out, const float* __restrict__ coefA,
    const float* __restrict__ coefB)
{
    const int i = blockIdx.x * 256 + threadIdx.x;
    if (i >= N_NODES * C_OUT / 4) return;
    const int c4 = (i * 4) & (C_OUT - 1);
    float4 o = ((float4*)out)[i];
    const float4 A = *(const float4*)(coefA + c4);
    const float4 B = *(const float4*)(coefB + c4);
    o.x = fmaxf(o.x * A.x + B.x, 0.f);
    o.y = fmaxf(o.y * A.y + B.y, 0.f);
    o.z = fmaxf(o.z * A.z + B.z, 0.f);
    o.w = fmaxf(o.w * A.w + B.w, 0.f);
    ((float4*)out)[i] = o;
}

extern "C" void kernel_launch(void* const* d_in, const int* in_sizes, int n_in,
                              void* d_out, int out_size, void* d_ws, size_t ws_size,
                              hipStream_t stream) {
    const float* x     = (const float*)d_in[0];
    const int*   src   = (const int*)d_in[1];
    const int*   dst   = (const int*)d_in[2];
    const float* theta = (const float*)d_in[3];
    const float* phi   = (const float*)d_in[4];
    const float* gamma = (const float*)d_in[5];
    const float* beta  = (const float*)d_in[6];
    float* out = (float*)d_out;

    // Workspace layout (16B-aligned chunks):
    char* ws = (char*)d_ws;
    const size_t uv_elems = (size_t)N_NODES * C_OUT;
    unsigned short* u = (unsigned short*)ws;                       // 25.6 MB fp16 slice-major
    unsigned short* v = u + uv_elems;                              // 25.6 MB fp16 slice-major
    float* sums   = (float*)(v + uv_elems);
    float* sumsq  = sums + C_OUT;
    float* coefA  = sumsq + C_OUT;
    float* coefB  = coefA + C_OUT;
    int*   deg    = (int*)(coefB + C_OUT);                         // contiguous for one memset
    int*   off    = deg + N_NODES;                                 // N_NODES+1 entries
    int*   cursor = off + N_NODES + 4;                             // pad keeps 16B align
    int*   edst   = cursor + N_NODES;                              // 3.2 MB
    int*   partials = edst + N_EDGES;                              // NBLK ints
    unsigned short* xb = (unsigned short*)(partials + NBLK + 8);   // 12.8 MB bf16
    unsigned short* wb = xb + (size_t)N_NODES * C_IN;              // 128 KB bf16

    // Zero sums/sumsq/coefs/deg in one shot (contiguous).
    hipMemsetAsync(sums, 0, (4 * C_OUT + N_NODES) * sizeof(int), stream);

    convert_xw<<<(XQ + WQ + 255) / 256, 256, 0, stream>>>(x, theta, phi, xb, wb);

    dim3 gA((N_NODES + 127) / 128, 4);
    gemm_mfma<<<gA, 256, 0, stream>>>(xb, wb, u, v);

    const int EB = (N_EDGES + 255) / 256;
    hist_src<<<EB, 256, 0, stream>>>(src, deg);
    scan_part<<<NBLK, 256, 0, stream>>>(deg, partials);
    scan_mid<<<1, 256, 0, stream>>>(partials, off);
    scan_fin<<<NBLK, 256, 0, stream>>>(deg, partials, off, cursor);
    scatter_edges<<<EB, 256, 0, stream>>>(src, dst, cursor, edst);

    const int chunks = (N_NODES + NPB - 1) / NPB;
    gather_slice<<<chunks * SL, 256, 0, stream>>>(
        off, edst, u, v, out, sums, sumsq);

    bn_prep<<<1, 256, 0, stream>>>(sums, sumsq, gamma, beta, coefA, coefB);
    bn_apply<<<(N_NODES * C_OUT / 4 + 255) / 256, 256, 0, stream>>>(
        out, coefA, coefB);
}

// Round 10
// 276.156 us; speedup vs baseline: 1.6720x; 1.0880x over previous
//
#include <hip/hip_runtime.h>

#define N_NODES 50000
#define N_EDGES 800000
#define C_IN 128
#define C_OUT 256
#define BN_EPS 1e-5f
#define NBLK ((N_NODES + 255) / 256)   // 196 scan blocks
#define SL 8                           // channel slices (== XCD count)
#define SLC 32                         // channels per slice
#define NPB 128                        // nodes per gather block (8 per 16-lane group)
#define PAD 8                          // LDS row pad (elems, keeps 16B align)

#define HB 782                         // hist/scatter blocks (1024 edges each)
#define GBX ((N_NODES + 127) / 128)    // 391 gemm row-tiles
#define GB (GBX * 4)                   // 1564 gemm blocks

using short8  = __attribute__((ext_vector_type(8))) short;
using floatx4 = __attribute__((ext_vector_type(4))) float;
using h2      = __attribute__((ext_vector_type(2))) _Float16;

union UH2 { unsigned int u; h2 h; };
union HS  { _Float16 f; unsigned short s; };

// packed f16 max -> v_pk_max_f16 (no header dependency; ROCm 7.2 lacks __hmax2)
__device__ __forceinline__ h2 pkmax(h2 a, h2 b) {
    return __builtin_elementwise_max(a, b);
}

// fp32 -> bf16 round-to-nearest-even (GEMM inputs only)
__device__ __forceinline__ unsigned short f2bf(float f) {
    unsigned int u = __float_as_uint(f);
    u = (u + 0x7fffu + ((u >> 16) & 1u)) >> 16;
    return (unsigned short)u;
}

#define XQ (N_NODES * C_IN / 4)        // 1,600,000 float4 of x
#define WQ (512 * C_IN / 4)            // 16,384 float4 of W'

// ---------------------------------------------------------------------------
// prep: fused [src-degree histogram] + [convert x->bf16, W'->bf16].
// Blocks 0..HB-1: hist (4 edges/thread, dispatched first — atomic-bound,
// overlaps the bw-bound convert). Blocks HB..: convert.
// Identity: theta@(xj-xi) + phi@xi = u[dst] + v[src]; relu/max commute so
// the edge pass only needs max over u rows.
// ---------------------------------------------------------------------------
__global__ __launch_bounds__(256) void prep(
    const float* __restrict__ x, const float* __restrict__ theta,
    const float* __restrict__ phi, const int* __restrict__ src,
    unsigned short* __restrict__ xb, unsigned short* __restrict__ wb,
    int* __restrict__ deg)
{
    const int tid = threadIdx.x;
    if (blockIdx.x < HB) {
        const int base = blockIdx.x * 1024 + tid;
        #pragma unroll
        for (int k = 0; k < 4; ++k) {
            int e = base + k * 256;
            if (e < N_EDGES) atomicAdd(&deg[src[e]], 1);
        }
        return;
    }
    int i = (blockIdx.x - HB) * 256 + tid;
    if (i < XQ) {
        float4 vv = ((const float4*)x)[i];
        ((ushort4*)xb)[i] = make_ushort4(f2bf(vv.x), f2bf(vv.y),
                                         f2bf(vv.z), f2bf(vv.w));
    } else if (i < XQ + WQ) {
        int j = i - XQ;
        float4 t;
        if (j < 256 * C_IN / 4) {
            t = ((const float4*)theta)[j];
        } else {
            int k = j - 256 * C_IN / 4;
            float4 th = ((const float4*)theta)[k];
            float4 ph = ((const float4*)phi)[k];
            t = make_float4(ph.x - th.x, ph.y - th.y, ph.z - th.z, ph.w - th.w);
        }
        ((ushort4*)wb)[j] = make_ushort4(f2bf(t.x), f2bf(t.y),
                                         f2bf(t.z), f2bf(t.w));
    }
}

// ---------------------------------------------------------------------------
// CSR scan: per-block partial sums, then scan_fin with the 196-entry
// mid-scan done redundantly per block in LDS (kills the scan_mid launch).
// ---------------------------------------------------------------------------
__global__ __launch_bounds__(256) void scan_part(
    const int* __restrict__ deg, int* __restrict__ partials)
{
    __shared__ int s[256];
    const int tid = threadIdx.x;
    int i = blockIdx.x * 256 + tid;
    s[tid] = (i < N_NODES) ? deg[i] : 0;
    __syncthreads();
    for (int d = 128; d > 0; d >>= 1) {
        if (tid < d) s[tid] += s[tid + d];
        __syncthreads();
    }
    if (tid == 0) partials[blockIdx.x] = s[0];
}

__global__ __launch_bounds__(256) void scan_fin(
    const int* __restrict__ deg, const int* __restrict__ partials,
    int* __restrict__ off, int* __restrict__ cursor)
{
    __shared__ int s[256];
    const int tid = threadIdx.x;

    // Inline mid-scan: inclusive scan of the 196 partials, redundant/block.
    int pv = (tid < NBLK) ? partials[tid] : 0;
    s[tid] = pv;
    __syncthreads();
    for (int d = 1; d < 256; d <<= 1) {
        int t = (tid >= d) ? s[tid - d] : 0;
        __syncthreads();
        s[tid] += t;
        __syncthreads();
    }
    const int blockPrefix = (blockIdx.x == 0) ? 0 : s[blockIdx.x - 1];
    const int total = s[NBLK - 1];
    __syncthreads();

    int i = blockIdx.x * 256 + tid;
    int v = (i < N_NODES) ? deg[i] : 0;
    s[tid] = v;
    __syncthreads();
    for (int d = 1; d < 256; d <<= 1) {
        int t = (tid >= d) ? s[tid - d] : 0;
        __syncthreads();
        s[tid] += t;
        __syncthreads();
    }
    int ex = s[tid] - v + blockPrefix;
    if (i < N_NODES) { off[i] = ex; cursor[i] = ex; }
    if (blockIdx.x == 0 && tid == 0) off[N_NODES] = total;
}

// ---------------------------------------------------------------------------
// gemm_scatter: fused [edge bucket-scatter] + [MFMA GEMM].
// Blocks 0..HB-1 (dispatched first): scatter 4 edges/thread — atomic/latency
// bound, overlaps the MFMA blocks on different pipes.
// Blocks HB..: GEMM M=50000, N=512, K=128, tile 128x128 (bx=b>>2, by=b&3 so
// consecutive blocks share the A-tile for L2 locality). K staged in 68KB LDS
// (2 blocks/CU). Outputs slice-major u/v fp16 for the XCD-local gather.
// Verified layouts: A-frag A[m=lane&15][k=quad*8+j]; B-frag B[k][n=lane&15];
// C/D col=lane&15, row=quad*4+reg (learn_hip m89/m91).
// ---------------------------------------------------------------------------
__global__ __launch_bounds__(256) void gemm_scatter(
    const unsigned short* __restrict__ xb,   // [N,128] bf16
    const unsigned short* __restrict__ wb,   // [512,128] bf16
    unsigned short* __restrict__ u,          // [SL][N][SLC] fp16
    unsigned short* __restrict__ v,          // [SL][N][SLC] fp16
    const int* __restrict__ src, const int* __restrict__ dst,
    int* __restrict__ cursor, int* __restrict__ edst)
{
    __shared__ unsigned short As[128][C_IN + PAD];
    __shared__ unsigned short Bs[128][C_IN + PAD];
    const int tid = threadIdx.x;

    if (blockIdx.x < HB) {
        const int base = blockIdx.x * 1024 + tid;
        int e0 = base, e1 = base + 256, e2 = base + 512, e3 = base + 768;
        int s0 = (e0 < N_EDGES) ? src[e0] : -1;
        int s1 = (e1 < N_EDGES) ? src[e1] : -1;
        int s2 = (e2 < N_EDGES) ? src[e2] : -1;
        int s3 = (e3 < N_EDGES) ? src[e3] : -1;
        int d0 = (e0 < N_EDGES) ? dst[e0] : 0;
        int d1 = (e1 < N_EDGES) ? dst[e1] : 0;
        int d2 = (e2 < N_EDGES) ? dst[e2] : 0;
        int d3 = (e3 < N_EDGES) ? dst[e3] : 0;
        if (s0 >= 0) edst[atomicAdd(&cursor[s0], 1)] = d0;
        if (s1 >= 0) edst[atomicAdd(&cursor[s1], 1)] = d1;
        if (s2 >= 0) edst[atomicAdd(&cursor[s2], 1)] = d2;
        if (s3 >= 0) edst[atomicAdd(&cursor[s3], 1)] = d3;
        return;
    }

    const int b = blockIdx.x - HB;
    const int bx = b >> 2;
    const int by = b & 3;

    // Stage A: 128 rows x 128 bf16 (2 threads/row, 8 uint4 each).
    {
        int r = tid >> 1;
        int cb = (tid & 1) * 64;
        int n = bx * 128 + r;
        if (n < N_NODES) {
            const uint4* sp = (const uint4*)(xb + (size_t)n * C_IN + cb);
            #pragma unroll
            for (int i = 0; i < 8; ++i) *(uint4*)&As[r][cb + i * 8] = sp[i];
        } else {
            uint4 z = make_uint4(0, 0, 0, 0);
            #pragma unroll
            for (int i = 0; i < 8; ++i) *(uint4*)&As[r][cb + i * 8] = z;
        }
    }
    // Stage B: 128 rows x 128 bf16.
    {
        int r = tid >> 1;
        int cb = (tid & 1) * 64;
        const uint4* sp = (const uint4*)(wb + (size_t)(by * 128 + r) * C_IN + cb);
        #pragma unroll
        for (int i = 0; i < 8; ++i) *(uint4*)&Bs[r][cb + i * 8] = sp[i];
    }
    __syncthreads();

    const int wave = tid >> 6;
    const int lane = tid & 63;
    const int l15 = lane & 15;
    const int quad = lane >> 4;

    floatx4 acc[2][8];
    #pragma unroll
    for (int mi = 0; mi < 2; ++mi)
        #pragma unroll
        for (int ni = 0; ni < 8; ++ni)
            acc[mi][ni] = (floatx4){0.f, 0.f, 0.f, 0.f};

    #pragma unroll
    for (int ks = 0; ks < 4; ++ks) {
        short8 a[2], bfr[8];
        #pragma unroll
        for (int mi = 0; mi < 2; ++mi)
            a[mi] = *(const short8*)&As[wave * 32 + mi * 16 + l15][ks * 32 + quad * 8];
        #pragma unroll
        for (int ni = 0; ni < 8; ++ni)
            bfr[ni] = *(const short8*)&Bs[ni * 16 + l15][ks * 32 + quad * 8];
        #pragma unroll
        for (int mi = 0; mi < 2; ++mi)
            #pragma unroll
            for (int ni = 0; ni < 8; ++ni)
                acc[mi][ni] = __builtin_amdgcn_mfma_f32_16x16x32_bf16(
                    a[mi], bfr[ni], acc[mi][ni], 0, 0, 0);
    }

    const bool is_u = (by < 2);   // 128-col tile never straddles 256
    #pragma unroll
    for (int mi = 0; mi < 2; ++mi) {
        #pragma unroll
        for (int r = 0; r < 4; ++r) {
            int n = bx * 128 + wave * 32 + mi * 16 + quad * 4 + r;
            if (n >= N_NODES) continue;
            #pragma unroll
            for (int ni = 0; ni < 8; ++ni) {
                int c = by * 128 + ni * 16 + l15;   // 0..511
                HS hv; hv.f = (_Float16)acc[mi][ni][r];
                if (is_u) {
                    int s = c >> 5, o = c & 31;
                    u[((size_t)s * N_NODES + n) * SLC + o] = hv.s;
                } else {
                    int c2 = c - C_OUT;
                    int s = c2 >> 5, o = c2 & 31;
                    v[((size_t)s * N_NODES + n) * SLC + o] = hv.s;
                }
            }
        }
    }
}

// ---------------------------------------------------------------------------
// Sliced gather-max. blockIdx & 7 = channel slice = XCD: XCD s only touches
// u-slice s (3.2 MB, its-L2-resident). One node per 16-lane group, 8-deep
// edge unroll. pkmax -> native v_pk_max_f16 (bf16 __hmax2 is emulated, R6).
// ---------------------------------------------------------------------------
__global__ __launch_bounds__(256) void gather_slice(
    const int* __restrict__ off, const int* __restrict__ edst,
    const unsigned short* __restrict__ u, const unsigned short* __restrict__ v,
    float* __restrict__ out, float* __restrict__ sums, float* __restrict__ sumsq)
{
    const int slice = blockIdx.x & 7;
    const int chunk = blockIdx.x >> 3;
    const int wave = threadIdx.x >> 6;
    const int lane = threadIdx.x & 63;
    const int grp = lane >> 4;        // node sub-group 0..3
    const int l16 = lane & 15;        // channel-pair index within slice
    const int loff = l16 * 4;         // byte offset within 64B u row
    const int g16 = wave * 4 + grp;   // block-level group id 0..15

    const char* ub = (const char*)(u + (size_t)slice * N_NODES * SLC);
    const unsigned short* vb = v + (size_t)slice * N_NODES * SLC;

    float s1_0 = 0.f, s1_1 = 0.f, s2_0 = 0.f, s2_1 = 0.f;

    #pragma unroll 1
    for (int i = 0; i < NPB / 16; ++i) {
        const int n = chunk * NPB + i * 16 + g16;
        if (n >= N_NODES) continue;
        const int start = off[n];
        const int end = off[n + 1];
        float a0 = 0.f, a1 = 0.f;
        if (end > start) {
            UH2 m; m.u = 0xFC00FC00u;           // packed f16 -inf
            const int nfull = (end - start) >> 3;
            const int* ep = edst + start;
            for (int it = 0; it < nfull; ++it) {
                int d0 = ep[0], d1 = ep[1], d2 = ep[2], d3 = ep[3];
                int d4 = ep[4], d5 = ep[5], d6 = ep[6], d7 = ep[7];
                UH2 w0, w1, w2, w3, w4, w5, w6, w7;
                w0.u = *(const unsigned int*)(ub + ((d0 << 6) | loff));
                w1.u = *(const unsigned int*)(ub + ((d1 << 6) | loff));
                w2.u = *(const unsigned int*)(ub + ((d2 << 6) | loff));
                w3.u = *(const unsigned int*)(ub + ((d3 << 6) | loff));
                w4.u = *(const unsigned int*)(ub + ((d4 << 6) | loff));
                w5.u = *(const unsigned int*)(ub + ((d5 << 6) | loff));
                w6.u = *(const unsigned int*)(ub + ((d6 << 6) | loff));
                w7.u = *(const unsigned int*)(ub + ((d7 << 6) | loff));
                h2 t0 = pkmax(pkmax(w0.h, w1.h), pkmax(w2.h, w3.h));
                h2 t1 = pkmax(pkmax(w4.h, w5.h), pkmax(w6.h, w7.h));
                m.h = pkmax(m.h, pkmax(t0, t1));
                ep += 8;
            }
            const int base = start + (nfull << 3);
            if (base < end) {                 // clamped tail (dups ok under max)
                const int lim = end - 1;
                int d0 = edst[base];
                int d1 = edst[min(base + 1, lim)], d2 = edst[min(base + 2, lim)];
                int d3 = edst[min(base + 3, lim)], d4 = edst[min(base + 4, lim)];
                int d5 = edst[min(base + 5, lim)], d6 = edst[min(base + 6, lim)];
                int d7 = edst[min(base + 7, lim)];
                UH2 w0, w1, w2, w3, w4, w5, w6, w7;
                w0.u = *(const unsigned int*)(ub + ((d0 << 6) | loff));
                w1.u = *(const unsigned int*)(ub + ((d1 << 6) | loff));
                w2.u = *(const unsigned int*)(ub + ((d2 << 6) | loff));
                w3.u = *(const unsigned int*)(ub + ((d3 << 6) | loff));
                w4.u = *(const unsigned int*)(ub + ((d4 << 6) | loff));
                w5.u = *(const unsigned int*)(ub + ((d5 << 6) | loff));
                w6.u = *(const unsigned int*)(ub + ((d6 << 6) | loff));
                w7.u = *(const unsigned int*)(ub + ((d7 << 6) | loff));
                h2 t0 = pkmax(pkmax(w0.h, w1.h), pkmax(w2.h, w3.h));
                h2 t1 = pkmax(pkmax(w4.h, w5.h), pkmax(w6.h, w7.h));
                m.h = pkmax(m.h, pkmax(t0, t1));
            }
            UH2 wv; wv.u = *(const unsigned int*)(vb + (size_t)n * SLC + l16 * 2);
            a0 = fmaxf((float)wv.h[0] + (float)m.h[0], 0.f);
            a1 = fmaxf((float)wv.h[1] + (float)m.h[1], 0.f);
        }
        *(float2*)(out + (size_t)n * C_OUT + slice * SLC + l16 * 2) =
            make_float2(a0, a1);
        s1_0 += a0; s1_1 += a1;
        s2_0 += a0 * a0; s2_1 += a1 * a1;
    }

    // Stats: reduce across the 16 groups; channels are disjoint per l16.
    __shared__ float red[16][16][4];
    red[g16][l16][0] = s1_0; red[g16][l16][1] = s1_1;
    red[g16][l16][2] = s2_0; red[g16][l16][3] = s2_1;
    __syncthreads();
    if (threadIdx.x < 16) {
        const int t = threadIdx.x;
        float r0 = 0.f, r1 = 0.f, r2 = 0.f, r3 = 0.f;
        #pragma unroll
        for (int g = 0; g < 16; ++g) {
            r0 += red[g][t][0]; r1 += red[g][t][1];
            r2 += red[g][t][2]; r3 += red[g][t][3];
        }
        const int c = slice * SLC + t * 2;
        atomicAdd(&sums[c + 0], r0);
        atomicAdd(&sums[c + 1], r1);
        atomicAdd(&sumsq[c + 0], r2);
        atomicAdd(&sumsq[c + 1], r3);
    }
}

// ---------------------------------------------------------------------------
// BN + ReLU, coefs computed redundantly per block in LDS (kills bn_prep).
// Each thread handles 4 float4 at stride 256 (all share one channel-quad).
// ---------------------------------------------------------------------------
__global__ __launch_bounds__(256) void bn_apply(
    float* __restrict__ out, const float* __restrict__ sums,
    const float* __restrict__ sumsq, const float* __restrict__ gamma,
    const float* __restrict__ beta)
{
    __shared__ float cA[C_OUT], cB[C_OUT];
    const int tid = threadIdx.x;
    {
        const float inv_n = 1.f / (float)N_NODES;
        const float mean = sums[tid] * inv_n;
        const float var = sumsq[tid] * inv_n - mean * mean;
        const float s = rsqrtf(var + BN_EPS) * gamma[tid];
        cA[tid] = s;
        cB[tid] = beta[tid] - mean * s;
    }
    __syncthreads();

    const int c4 = (tid * 4) & (C_OUT - 1);
    const float4 A = *(const float4*)(cA + c4);
    const float4 B = *(const float4*)(cB + c4);
    const int base = blockIdx.x * 1024 + tid;
    #pragma unroll
    for (int k = 0; k < 4; ++k) {
        const int i = base + k * 256;
        float4 o = ((float4*)out)[i];
        o.x = fmaxf(o.x * A.x + B.x, 0.f);
        o.y = fmaxf(o.y * A.y + B.y, 0.f);
        o.z = fmaxf(o.z * A.z + B.z, 0.f);
        o.w = fmaxf(o.w * A.w + B.w, 0.f);
        ((float4*)out)[i] = o;
    }
}

extern "C" void kernel_launch(void* const* d_in, const int* in_sizes, int n_in,
                              void* d_out, int out_size, void* d_ws, size_t ws_size,
                              hipStream_t stream) {
    const float* x     = (const float*)d_in[0];
    const int*   src   = (const int*)d_in[1];
    const int*   dst   = (const int*)d_in[2];
    const float* theta = (const float*)d_in[3];
    const float* phi   = (const float*)d_in[4];
    const float* gamma = (const float*)d_in[5];
    const float* beta  = (const float*)d_in[6];
    float* out = (float*)d_out;

    // Workspace layout (16B-aligned chunks):
    char* ws = (char*)d_ws;
    const size_t uv_elems = (size_t)N_NODES * C_OUT;
    unsigned short* u = (unsigned short*)ws;                       // 25.6 MB fp16 slice-major
    unsigned short* v = u + uv_elems;                              // 25.6 MB fp16 slice-major
    float* sums   = (float*)(v + uv_elems);
    float* sumsq  = sums + C_OUT;
    int*   deg    = (int*)(sumsq + C_OUT);                         // contiguous for one memset
    int*   off    = deg + N_NODES;                                 // N_NODES+1 entries
    int*   cursor = off + N_NODES + 4;                             // pad keeps 16B align
    int*   edst   = cursor + N_NODES;                              // 3.2 MB
    int*   partials = edst + N_EDGES;                              // NBLK ints
    unsigned short* xb = (unsigned short*)(partials + NBLK + 8);   // 12.8 MB bf16
    unsigned short* wb = xb + (size_t)N_NODES * C_IN;              // 128 KB bf16

    // Zero sums/sumsq/deg in one shot (contiguous).
    hipMemsetAsync(sums, 0, (2 * C_OUT + N_NODES) * sizeof(int), stream);

    // Fused hist + convert.
    prep<<<HB + (XQ + WQ + 255) / 256, 256, 0, stream>>>(
        x, theta, phi, src, xb, wb, deg);

    scan_part<<<NBLK, 256, 0, stream>>>(deg, partials);
    scan_fin<<<NBLK, 256, 0, stream>>>(deg, partials, off, cursor);

    // Fused scatter + MFMA GEMM.
    gemm_scatter<<<HB + GB, 256, 0, stream>>>(
        xb, wb, u, v, src, dst, cursor, edst);

    const int chunks = (N_NODES + NPB - 1) / NPB;
    gather_slice<<<chunks * SL, 256, 0, stream>>>(
        off, edst, u, v, out, sums, sumsq);

    bn_apply<<<(N_NODES * C_OUT / 4) / 1024, 256, 0, stream>>>(
        out, sums, sumsq, gamma, beta);
}

// Round 11
// 270.709 us; speedup vs baseline: 1.7056x; 1.0201x over previous
//
#include <hip/hip_runtime.h>

#define N_NODES 50000
#define N_EDGES 800000
#define C_IN 128
#define C_OUT 256
#define BN_EPS 1e-5f
#define NBLK ((N_NODES + 255) / 256)   // 196 scan blocks
#define SL 8                           // channel slices (== XCD count)
#define SLC 32                         // channels per slice
#define NPB 128                        // nodes per gather block (8 per 16-lane group)
#define PAD 8                          // LDS row pad (elems, keeps 16B align)

#define HB 782                         // hist/scatter blocks (1024 edges each)
#define GBX ((N_NODES + 127) / 128)    // 391 gemm row-tiles
#define GB (GBX * 4)                   // 1564 gemm blocks

using short8  = __attribute__((ext_vector_type(8))) short;
using floatx4 = __attribute__((ext_vector_type(4))) float;
using h2      = __attribute__((ext_vector_type(2))) _Float16;

union UH2 { unsigned int u; h2 h; };
union HS  { _Float16 f; unsigned short s; };

// packed f16 max -> v_pk_max_f16 (no header dependency; ROCm 7.2 lacks __hmax2)
__device__ __forceinline__ h2 pkmax(h2 a, h2 b) {
    return __builtin_elementwise_max(a, b);
}

// fp32 -> bf16 round-to-nearest-even (GEMM inputs only)
__device__ __forceinline__ unsigned short f2bf(float f) {
    unsigned int u = __float_as_uint(f);
    u = (u + 0x7fffu + ((u >> 16) & 1u)) >> 16;
    return (unsigned short)u;
}

#define XQ (N_NODES * C_IN / 4)        // 1,600,000 float4 of x
#define WQ (512 * C_IN / 4)            // 16,384 float4 of W'

// ---------------------------------------------------------------------------
// prep: fused [src-degree histogram] + [convert x->bf16, W'->bf16].
// Blocks 0..HB-1: hist (4 edges/thread, dispatched first — atomic-bound,
// overlaps the bw-bound convert). Blocks HB..: convert.
// Identity: theta@(xj-xi) + phi@xi = u[dst] + v[src]; relu/max commute so
// the edge pass only needs max over u rows.
// ---------------------------------------------------------------------------
__global__ __launch_bounds__(256) void prep(
    const float* __restrict__ x, const float* __restrict__ theta,
    const float* __restrict__ phi, const int* __restrict__ src,
    unsigned short* __restrict__ xb, unsigned short* __restrict__ wb,
    int* __restrict__ deg)
{
    const int tid = threadIdx.x;
    if (blockIdx.x < HB) {
        const int base = blockIdx.x * 1024 + tid;
        #pragma unroll
        for (int k = 0; k < 4; ++k) {
            int e = base + k * 256;
            if (e < N_EDGES) atomicAdd(&deg[src[e]], 1);
        }
        return;
    }
    int i = (blockIdx.x - HB) * 256 + tid;
    if (i < XQ) {
        float4 vv = ((const float4*)x)[i];
        ((ushort4*)xb)[i] = make_ushort4(f2bf(vv.x), f2bf(vv.y),
                                         f2bf(vv.z), f2bf(vv.w));
    } else if (i < XQ + WQ) {
        int j = i - XQ;
        float4 t;
        if (j < 256 * C_IN / 4) {
            t = ((const float4*)theta)[j];
        } else {
            int k = j - 256 * C_IN / 4;
            float4 th = ((const float4*)theta)[k];
            float4 ph = ((const float4*)phi)[k];
            t = make_float4(ph.x - th.x, ph.y - th.y, ph.z - th.z, ph.w - th.w);
        }
        ((ushort4*)wb)[j] = make_ushort4(f2bf(t.x), f2bf(t.y),
                                         f2bf(t.z), f2bf(t.w));
    }
}

// ---------------------------------------------------------------------------
// CSR scan: per-block partial sums, then scan_fin with the 196-entry
// mid-scan done redundantly per block in LDS (kills the scan_mid launch).
// ---------------------------------------------------------------------------
__global__ __launch_bounds__(256) void scan_part(
    const int* __restrict__ deg, int* __restrict__ partials)
{
    __shared__ int s[256];
    const int tid = threadIdx.x;
    int i = blockIdx.x * 256 + tid;
    s[tid] = (i < N_NODES) ? deg[i] : 0;
    __syncthreads();
    for (int d = 128; d > 0; d >>= 1) {
        if (tid < d) s[tid] += s[tid + d];
        __syncthreads();
    }
    if (tid == 0) partials[blockIdx.x] = s[0];
}

__global__ __launch_bounds__(256) void scan_fin(
    const int* __restrict__ deg, const int* __restrict__ partials,
    int* __restrict__ off, int* __restrict__ cursor)
{
    __shared__ int s[256];
    const int tid = threadIdx.x;

    // Inline mid-scan: inclusive scan of the 196 partials, redundant/block.
    int pv = (tid < NBLK) ? partials[tid] : 0;
    s[tid] = pv;
    __syncthreads();
    for (int d = 1; d < 256; d <<= 1) {
        int t = (tid >= d) ? s[tid - d] : 0;
        __syncthreads();
        s[tid] += t;
        __syncthreads();
    }
    const int blockPrefix = (blockIdx.x == 0) ? 0 : s[blockIdx.x - 1];
    const int total = s[NBLK - 1];
    __syncthreads();

    int i = blockIdx.x * 256 + tid;
    int v = (i < N_NODES) ? deg[i] : 0;
    s[tid] = v;
    __syncthreads();
    for (int d = 1; d < 256; d <<= 1) {
        int t = (tid >= d) ? s[tid - d] : 0;
        __syncthreads();
        s[tid] += t;
        __syncthreads();
    }
    int ex = s[tid] - v + blockPrefix;
    if (i < N_NODES) { off[i] = ex; cursor[i] = ex; }
    if (blockIdx.x == 0 && tid == 0) off[N_NODES] = total;
}

// ---------------------------------------------------------------------------
// gemm_scatter v2: fused [edge bucket-scatter] + [MFMA GEMM].
// R10 lesson: 70KB LDS capped the WHOLE kernel (incl. scatter blocks) at
// 2 blocks/CU with both pipes idle. Fix: drop the A-tile staging — A
// fragments load directly from global (row clamped to N-1; OOB rows are
// computed but never stored). A-tile stays L2-hot across the 4 consecutive
// by-blocks sharing bx. B-tile stays in LDS (34KB, shared by all 4 waves).
// -> 4 blocks/CU, 16 waves, one barrier.
// Verified layouts: A-frag A[m=lane&15][k=quad*8+j]; B-frag B[k][n=lane&15];
// C/D col=lane&15, row=quad*4+reg (learn_hip m89/m91).
// ---------------------------------------------------------------------------
__global__ __launch_bounds__(256) void gemm_scatter(
    const unsigned short* __restrict__ xb,   // [N,128] bf16
    const unsigned short* __restrict__ wb,   // [512,128] bf16
    unsigned short* __restrict__ u,          // [SL][N][SLC] fp16
    unsigned short* __restrict__ v,          // [SL][N][SLC] fp16
    const int* __restrict__ src, const int* __restrict__ dst,
    int* __restrict__ cursor, int* __restrict__ edst)
{
    __shared__ unsigned short Bs[128][C_IN + PAD];
    const int tid = threadIdx.x;

    if (blockIdx.x < HB) {
        const int base = blockIdx.x * 1024 + tid;
        int e0 = base, e1 = base + 256, e2 = base + 512, e3 = base + 768;
        int s0 = (e0 < N_EDGES) ? src[e0] : -1;
        int s1 = (e1 < N_EDGES) ? src[e1] : -1;
        int s2 = (e2 < N_EDGES) ? src[e2] : -1;
        int s3 = (e3 < N_EDGES) ? src[e3] : -1;
        int d0 = (e0 < N_EDGES) ? dst[e0] : 0;
        int d1 = (e1 < N_EDGES) ? dst[e1] : 0;
        int d2 = (e2 < N_EDGES) ? dst[e2] : 0;
        int d3 = (e3 < N_EDGES) ? dst[e3] : 0;
        if (s0 >= 0) edst[atomicAdd(&cursor[s0], 1)] = d0;
        if (s1 >= 0) edst[atomicAdd(&cursor[s1], 1)] = d1;
        if (s2 >= 0) edst[atomicAdd(&cursor[s2], 1)] = d2;
        if (s3 >= 0) edst[atomicAdd(&cursor[s3], 1)] = d3;
        return;
    }

    const int b = blockIdx.x - HB;
    const int bx = b >> 2;
    const int by = b & 3;
    const int wave = tid >> 6;
    const int lane = tid & 63;
    const int l15 = lane & 15;
    const int quad = lane >> 4;

    // Stage B: 128 rows x 128 bf16 (2 threads/row, 8 uint4 each).
    {
        int r = tid >> 1;
        int cb = (tid & 1) * 64;
        const uint4* sp = (const uint4*)(wb + (size_t)(by * 128 + r) * C_IN + cb);
        #pragma unroll
        for (int i = 0; i < 8; ++i) *(uint4*)&Bs[r][cb + i * 8] = sp[i];
    }

    // A fragment base pointers (rows clamped; OOB rows never stored).
    const int n0 = bx * 128 + wave * 32 + l15;
    const unsigned short* arow0 = xb + (size_t)min(n0,      N_NODES - 1) * C_IN + quad * 8;
    const unsigned short* arow1 = xb + (size_t)min(n0 + 16, N_NODES - 1) * C_IN + quad * 8;

    __syncthreads();

    floatx4 acc[2][8];
    #pragma unroll
    for (int mi = 0; mi < 2; ++mi)
        #pragma unroll
        for (int ni = 0; ni < 8; ++ni)
            acc[mi][ni] = (floatx4){0.f, 0.f, 0.f, 0.f};

    #pragma unroll
    for (int ks = 0; ks < 4; ++ks) {
        short8 a[2], bfr[8];
        a[0] = *(const short8*)(arow0 + ks * 32);
        a[1] = *(const short8*)(arow1 + ks * 32);
        #pragma unroll
        for (int ni = 0; ni < 8; ++ni)
            bfr[ni] = *(const short8*)&Bs[ni * 16 + l15][ks * 32 + quad * 8];
        #pragma unroll
        for (int mi = 0; mi < 2; ++mi)
            #pragma unroll
            for (int ni = 0; ni < 8; ++ni)
                acc[mi][ni] = __builtin_amdgcn_mfma_f32_16x16x32_bf16(
                    a[mi], bfr[ni], acc[mi][ni], 0, 0, 0);
    }

    const bool is_u = (by < 2);   // 128-col tile never straddles 256
    #pragma unroll
    for (int mi = 0; mi < 2; ++mi) {
        #pragma unroll
        for (int r = 0; r < 4; ++r) {
            int n = bx * 128 + wave * 32 + mi * 16 + quad * 4 + r;
            if (n >= N_NODES) continue;
            #pragma unroll
            for (int ni = 0; ni < 8; ++ni) {
                int c = by * 128 + ni * 16 + l15;   // 0..511
                HS hv; hv.f = (_Float16)acc[mi][ni][r];
                if (is_u) {
                    int s = c >> 5, o = c & 31;
                    u[((size_t)s * N_NODES + n) * SLC + o] = hv.s;
                } else {
                    int c2 = c - C_OUT;
                    int s = c2 >> 5, o = c2 & 31;
                    v[((size_t)s * N_NODES + n) * SLC + o] = hv.s;
                }
            }
        }
    }
}

// ---------------------------------------------------------------------------
// Sliced gather-max. blockIdx & 7 = channel slice = XCD: XCD s only touches
// u-slice s (3.2 MB, its-L2-resident). One node per 16-lane group, 8-deep
// edge unroll. pkmax -> native v_pk_max_f16 (bf16 __hmax2 is emulated, R6).
// ---------------------------------------------------------------------------
__global__ __launch_bounds__(256) void gather_slice(
    const int* __restrict__ off, const int* __restrict__ edst,
    const unsigned short* __restrict__ u, const unsigned short* __restrict__ v,
    float* __restrict__ out, float* __restrict__ sums, float* __restrict__ sumsq)
{
    const int slice = blockIdx.x & 7;
    const int chunk = blockIdx.x >> 3;
    const int wave = threadIdx.x >> 6;
    const int lane = threadIdx.x & 63;
    const int grp = lane >> 4;        // node sub-group 0..3
    const int l16 = lane & 15;        // channel-pair index within slice
    const int loff = l16 * 4;         // byte offset within 64B u row
    const int g16 = wave * 4 + grp;   // block-level group id 0..15

    const char* ub = (const char*)(u + (size_t)slice * N_NODES * SLC);
    const unsigned short* vb = v + (size_t)slice * N_NODES * SLC;

    float s1_0 = 0.f, s1_1 = 0.f, s2_0 = 0.f, s2_1 = 0.f;

    #pragma unroll 1
    for (int i = 0; i < NPB / 16; ++i) {
        const int n = chunk * NPB + i * 16 + g16;
        if (n >= N_NODES) continue;
        const int start = off[n];
        const int end = off[n + 1];
        float a0 = 0.f, a1 = 0.f;
        if (end > start) {
            UH2 m; m.u = 0xFC00FC00u;           // packed f16 -inf
            const int nfull = (end - start) >> 3;
            const int* ep = edst + start;
            for (int it = 0; it < nfull; ++it) {
                int d0 = ep[0], d1 = ep[1], d2 = ep[2], d3 = ep[3];
                int d4 = ep[4], d5 = ep[5], d6 = ep[6], d7 = ep[7];
                UH2 w0, w1, w2, w3, w4, w5, w6, w7;
                w0.u = *(const unsigned int*)(ub + ((d0 << 6) | loff));
                w1.u = *(const unsigned int*)(ub + ((d1 << 6) | loff));
                w2.u = *(const unsigned int*)(ub + ((d2 << 6) | loff));
                w3.u = *(const unsigned int*)(ub + ((d3 << 6) | loff));
                w4.u = *(const unsigned int*)(ub + ((d4 << 6) | loff));
                w5.u = *(const unsigned int*)(ub + ((d5 << 6) | loff));
                w6.u = *(const unsigned int*)(ub + ((d6 << 6) | loff));
                w7.u = *(const unsigned int*)(ub + ((d7 << 6) | loff));
                h2 t0 = pkmax(pkmax(w0.h, w1.h), pkmax(w2.h, w3.h));
                h2 t1 = pkmax(pkmax(w4.h, w5.h), pkmax(w6.h, w7.h));
                m.h = pkmax(m.h, pkmax(t0, t1));
                ep += 8;
            }
            const int base = start + (nfull << 3);
            if (base < end) {                 // clamped tail (dups ok under max)
                const int lim = end - 1;
                int d0 = edst[base];
                int d1 = edst[min(base + 1, lim)], d2 = edst[min(base + 2, lim)];
                int d3 = edst[min(base + 3, lim)], d4 = edst[min(base + 4, lim)];
                int d5 = edst[min(base + 5, lim)], d6 = edst[min(base + 6, lim)];
                int d7 = edst[min(base + 7, lim)];
                UH2 w0, w1, w2, w3, w4, w5, w6, w7;
                w0.u = *(const unsigned int*)(ub + ((d0 << 6) | loff));
                w1.u = *(const unsigned int*)(ub + ((d1 << 6) | loff));
                w2.u = *(const unsigned int*)(ub + ((d2 << 6) | loff));
                w3.u = *(const unsigned int*)(ub + ((d3 << 6) | loff));
                w4.u = *(const unsigned int*)(ub + ((d4 << 6) | loff));
                w5.u = *(const unsigned int*)(ub + ((d5 << 6) | loff));
                w6.u = *(const unsigned int*)(ub + ((d6 << 6) | loff));
                w7.u = *(const unsigned int*)(ub + ((d7 << 6) | loff));
                h2 t0 = pkmax(pkmax(w0.h, w1.h), pkmax(w2.h, w3.h));
                h2 t1 = pkmax(pkmax(w4.h, w5.h), pkmax(w6.h, w7.h));
                m.h = pkmax(m.h, pkmax(t0, t1));
            }
            UH2 wv; wv.u = *(const unsigned int*)(vb + (size_t)n * SLC + l16 * 2);
            a0 = fmaxf((float)wv.h[0] + (float)m.h[0], 0.f);
            a1 = fmaxf((float)wv.h[1] + (float)m.h[1], 0.f);
        }
        *(float2*)(out + (size_t)n * C_OUT + slice * SLC + l16 * 2) =
            make_float2(a0, a1);
        s1_0 += a0; s1_1 += a1;
        s2_0 += a0 * a0; s2_1 += a1 * a1;
    }

    // Stats: reduce across the 16 groups; channels are disjoint per l16.
    __shared__ float red[16][16][4];
    red[g16][l16][0] = s1_0; red[g16][l16][1] = s1_1;
    red[g16][l16][2] = s2_0; red[g16][l16][3] = s2_1;
    __syncthreads();
    if (threadIdx.x < 16) {
        const int t = threadIdx.x;
        float r0 = 0.f, r1 = 0.f, r2 = 0.f, r3 = 0.f;
        #pragma unroll
        for (int g = 0; g < 16; ++g) {
            r0 += red[g][t][0]; r1 += red[g][t][1];
            r2 += red[g][t][2]; r3 += red[g][t][3];
        }
        const int c = slice * SLC + t * 2;
        atomicAdd(&sums[c + 0], r0);
        atomicAdd(&sums[c + 1], r1);
        atomicAdd(&sumsq[c + 0], r2);
        atomicAdd(&sumsq[c + 1], r3);
    }
}

// ---------------------------------------------------------------------------
// BN + ReLU, coefs computed redundantly per block in LDS (kills bn_prep).
// Each thread handles 4 float4 at stride 256 (all share one channel-quad).
// ---------------------------------------------------------------------------
__global__ __launch_bounds__(256) void bn_apply(
    float* __restrict__ out, const float* __restrict__ sums,
    const float* __restrict__ sumsq, const float* __restrict__ gamma,
    const float* __restrict__ beta)
{
    __shared__ float cA[C_OUT], cB[C_OUT];
    const int tid = threadIdx.x;
    {
        const float inv_n = 1.f / (float)N_NODES;
        const float mean = sums[tid] * inv_n;
        const float var = sumsq[tid] * inv_n - mean * mean;
        const float s = rsqrtf(var + BN_EPS) * gamma[tid];
        cA[tid] = s;
        cB[tid] = beta[tid] - mean * s;
    }
    __syncthreads();

    const int c4 = (tid * 4) & (C_OUT - 1);
    const float4 A = *(const float4*)(cA + c4);
    const float4 B = *(const float4*)(cB + c4);
    const int base = blockIdx.x * 1024 + tid;
    #pragma unroll
    for (int k = 0; k < 4; ++k) {
        const int i = base + k * 256;
        float4 o = ((float4*)out)[i];
        o.x = fmaxf(o.x * A.x + B.x, 0.f);
        o.y = fmaxf(o.y * A.y + B.y, 0.f);
        o.z = fmaxf(o.z * A.z + B.z, 0.f);
        o.w = fmaxf(o.w * A.w + B.w, 0.f);
        ((float4*)out)[i] = o;
    }
}

extern "C" void kernel_launch(void* const* d_in, const int* in_sizes, int n_in,
                              void* d_out, int out_size, void* d_ws, size_t ws_size,
                              hipStream_t stream) {
    const float* x     = (const float*)d_in[0];
    const int*   src   = (const int*)d_in[1];
    const int*   dst   = (const int*)d_in[2];
    const float* theta = (const float*)d_in[3];
    const float* phi   = (const float*)d_in[4];
    const float* gamma = (const float*)d_in[5];
    const float* beta  = (const float*)d_in[6];
    float* out = (float*)d_out;

    // Workspace layout (16B-aligned chunks):
    char* ws = (char*)d_ws;
    const size_t uv_elems = (size_t)N_NODES * C_OUT;
    unsigned short* u = (unsigned short*)ws;                       // 25.6 MB fp16 slice-major
    unsigned short* v = u + uv_elems;                              // 25.6 MB fp16 slice-major
    float* sums   = (float*)(v + uv_elems);
    float* sumsq  = sums + C_OUT;
    int*   deg    = (int*)(sumsq + C_OUT);                         // contiguous for one memset
    int*   off    = deg + N_NODES;                                 // N_NODES+1 entries
    int*   cursor = off + N_NODES + 4;                             // pad keeps 16B align
    int*   edst   = cursor + N_NODES;                              // 3.2 MB
    int*   partials = edst + N_EDGES;                              // NBLK ints
    unsigned short* xb = (unsigned short*)(partials + NBLK + 8);   // 12.8 MB bf16
    unsigned short* wb = xb + (size_t)N_NODES * C_IN;              // 128 KB bf16

    // Zero sums/sumsq/deg in one shot (contiguous).
    hipMemsetAsync(sums, 0, (2 * C_OUT + N_NODES) * sizeof(int), stream);

    // Fused hist + convert.
    prep<<<HB + (XQ + WQ + 255) / 256, 256, 0, stream>>>(
        x, theta, phi, src, xb, wb, deg);

    scan_part<<<NBLK, 256, 0, stream>>>(deg, partials);
    scan_fin<<<NBLK, 256, 0, stream>>>(deg, partials, off, cursor);

    // Fused scatter + MFMA GEMM (A direct-from-global, B staged in 34KB LDS).
    gemm_scatter<<<HB + GB, 256, 0, stream>>>(
        xb, wb, u, v, src, dst, cursor, edst);

    const int chunks = (N_NODES + NPB - 1) / NPB;
    gather_slice<<<chunks * SL, 256, 0, stream>>>(
        off, edst, u, v, out, sums, sumsq);

    bn_apply<<<(N_NODES * C_OUT / 4) / 1024, 256, 0, stream>>>(
        out, sums, sumsq, gamma, beta);
}